// Round 1
// baseline (10806.786 us; speedup 1.0000x reference)
//
#include <hip/hip_runtime.h>

#define S_ 512
#define B_ 64
#define I_ 512
#define H_ 1024
#define O_ 512
#define C_ 1536   // I_ + H_
#define NG_ 4096  // 4*H_

typedef unsigned short u16;
typedef __attribute__((ext_vector_type(8))) short bf16x8;
typedef __attribute__((ext_vector_type(8))) unsigned short u16x8;
typedef __attribute__((ext_vector_type(4))) float f32x4;

__device__ __forceinline__ u16 f2bf(float f) {
    union { float f; unsigned int u; } v; v.f = f;
    unsigned int u = v.u;
    unsigned int r = (u + 0x7fffu + ((u >> 16) & 1u)) >> 16;
    return (u16)r;
}
__device__ __forceinline__ float bf2f(u16 h) {
    union { unsigned int u; float f; } v; v.u = ((unsigned int)h) << 16;
    return v.f;
}
__device__ __forceinline__ float sigm(float x) { return 1.0f / (1.0f + __expf(-x)); }

// ---- packing kernels -------------------------------------------------------

__global__ void k_pack_w(const float* __restrict__ Wf, const float* __restrict__ Wi,
                         const float* __restrict__ Wo, const float* __restrict__ Wg,
                         u16* __restrict__ Wall) {
    size_t i8 = ((size_t)blockIdx.x * blockDim.x + threadIdx.x) * 8;
    if (i8 >= (size_t)NG_ * C_) return;
    size_t n = i8 / C_;
    size_t k = i8 - n * C_;
    const float* Ws[4] = {Wf, Wi, Wo, Wg};
    const float* src = Ws[n >> 10] + (n & 1023) * C_ + k;
    u16x8 o;
#pragma unroll
    for (int j = 0; j < 8; j++) o[j] = f2bf(src[j]);
    *(u16x8*)(Wall + i8) = o;
}

__global__ void k_pack_wy(const float* __restrict__ Wy,
                          u16* __restrict__ hi, u16* __restrict__ lo) {
    size_t i8 = ((size_t)blockIdx.x * blockDim.x + threadIdx.x) * 8;
    if (i8 >= (size_t)O_ * H_) return;
    u16x8 oh, ol;
#pragma unroll
    for (int j = 0; j < 8; j++) {
        float v = Wy[i8 + j];
        oh[j] = f2bf(v);
        ol[j] = f2bf(v - bf2f(oh[j]));
    }
    *(u16x8*)(hi + i8) = oh;
    *(u16x8*)(lo + i8) = ol;
}

__global__ void k_pack_x(const float* __restrict__ x, u16* __restrict__ xb) {
    size_t i8 = ((size_t)blockIdx.x * blockDim.x + threadIdx.x) * 8;
    if (i8 >= (size_t)S_ * B_ * I_) return;
    u16x8 o;
#pragma unroll
    for (int j = 0; j < 8; j++) o[j] = f2bf(x[i8 + j]);
    *(u16x8*)(xb + i8) = o;
}

// ---- persistent LSTM: all 512 steps in one kernel --------------------------
// 256 blocks x 256 threads (1..2 blocks/CU). Block owns 4 hidden units x 4
// gates x full K=1536: its 48 KB weight slice lives in LDS for the whole
// sequence (zero weight re-fetch; old design pulled 192 KB/CU/step from L2).
// Wave w owns batch rows [16w,16w+16) x all 16 gate-units x full K:
// 48 chained MFMAs, no cross-wave reduce. c-state = 1 register/thread.
// Steps separated by a one-way release/acquire flag sync (agent scope,
// 8-way-split counter per t). x-part (k<512) of the GEMM is h-independent
// and is computed BEFORE the spin to hide sync latency.
// __launch_bounds__(256,2) caps VGPRs at 256 so >=2 blocks/CU fit ->
// all 256 blocks co-resident under greedy dispatch (no coop-launch needed).
__global__ __launch_bounds__(256, 2) void k_lstm(
    const u16* __restrict__ Wall,   // [4096][1536] bf16
    const u16* __restrict__ xbf,    // [S][64][512] bf16
    const float* __restrict__ bfv, const float* __restrict__ biv,
    const float* __restrict__ bov, const float* __restrict__ bgv,
    u16* __restrict__ hhi,          // [S+1][64][1024] bf16
    u16* __restrict__ hlo,          // [S+1][64][1024] bf16 residual
    int* __restrict__ cnt)          // [S][8] step-completion counters
{
    __shared__ __align__(16) u16 wlds[48 * 64 * 8];  // 48 KB: [chunk][lane][8]
    __shared__ float ex[4][16][17];                  // per-wave gate exchange

    const int tid = threadIdx.x;
    const int w = tid >> 6;          // wave -> batch rows [16w,16w+16)
    const int lane = tid & 63;
    const int la = lane & 15;        // A row (batch) / B row (gate-unit)
    const int q = lane >> 4;         // k sub-offset group / C row group
    const int blk = blockIdx.x;      // owns hidden units [4*blk, 4*blk+4)

    // ---- stage the weight slice into LDS, MFMA fragment order ----
    // B-tile row p (0..15) = gate-unit (g = p&3, v = p>>2); lane l of chunk ch
    // reads W[p=l&15][k = 32*ch + 8*(l>>4) + j] at wlds[(ch*64+l)*8].
    {
        const int p = tid >> 4;
        const int g = p & 3, v = p >> 2;
        const u16* wrow = Wall + (size_t)(g * H_ + blk * 4 + v) * C_;
        const int kb = tid & 15;
#pragma unroll
        for (int i = 0; i < 12; i++) {
            int k8 = kb + (i << 4);                      // 0..191
            bf16x8 wv = *(const bf16x8*)(wrow + (k8 << 3));
            int off16 = ((k8 >> 2) << 6) + ((k8 & 3) << 4) + p;
            *(bf16x8*)(&wlds[(size_t)off16 << 3]) = wv;
        }
    }

    // epilogue ownership: lane -> (batch b2, unit j2); c lives in a register
    const int m2 = lane & 15;
    const int v2 = lane >> 4;
    const int b2 = w * 16 + m2;
    const int j2 = blk * 4 + v2;
    const float bF = bfv[j2], bI = biv[j2], bO = bov[j2], bG = bgv[j2];
    float c_reg = 0.f;

    __syncthreads();   // wlds ready (cross-wave)

    for (int t = 0; t < S_; t++) {
        const u16* xr = xbf + ((size_t)t * B_ + w * 16 + la) * I_ + (q << 3);
        f32x4 a0 = (f32x4){0.f,0.f,0.f,0.f};
        f32x4 a1 = (f32x4){0.f,0.f,0.f,0.f};
        f32x4 a2 = (f32x4){0.f,0.f,0.f,0.f};
        f32x4 a3 = (f32x4){0.f,0.f,0.f,0.f};

        // x-part (chunks 0..15): independent of h -> runs before the sync
#pragma unroll
        for (int ch = 0; ch < 16; ch += 4) {
            bf16x8 x0 = *(const bf16x8*)(xr + (ch << 5));
            bf16x8 x1 = *(const bf16x8*)(xr + ((ch + 1) << 5));
            bf16x8 x2 = *(const bf16x8*)(xr + ((ch + 2) << 5));
            bf16x8 x3 = *(const bf16x8*)(xr + ((ch + 3) << 5));
            bf16x8 w0 = *(const bf16x8*)(&wlds[(size_t)((ch    ) * 64 + lane) << 3]);
            bf16x8 w1 = *(const bf16x8*)(&wlds[(size_t)((ch + 1) * 64 + lane) << 3]);
            bf16x8 w2 = *(const bf16x8*)(&wlds[(size_t)((ch + 2) * 64 + lane) << 3]);
            bf16x8 w3 = *(const bf16x8*)(&wlds[(size_t)((ch + 3) * 64 + lane) << 3]);
            a0 = __builtin_amdgcn_mfma_f32_16x16x32_bf16(x0, w0, a0, 0, 0, 0);
            a1 = __builtin_amdgcn_mfma_f32_16x16x32_bf16(x1, w1, a1, 0, 0, 0);
            a2 = __builtin_amdgcn_mfma_f32_16x16x32_bf16(x2, w2, a2, 0, 0, 0);
            a3 = __builtin_amdgcn_mfma_f32_16x16x32_bf16(x3, w3, a3, 0, 0, 0);
        }

        // wait for h(t): all 256 blocks finished step t-1
        if (t > 0) {
            if (tid == 0) {
                const int* cl = cnt + ((t - 1) << 3);
                for (;;) {
                    int s = 0;
#pragma unroll
                    for (int u = 0; u < 8; u++)
                        s += __hip_atomic_load(&cl[u], __ATOMIC_RELAXED,
                                               __HIP_MEMORY_SCOPE_AGENT);
                    if (s == 256) break;
                    __builtin_amdgcn_s_sleep(1);
                }
            }
            __syncthreads();
            // acquire: invalidate stale L1/L2 before reading cross-XCD h
            (void)__hip_atomic_load(&cnt[(size_t)(t - 1) << 3], __ATOMIC_ACQUIRE,
                                    __HIP_MEMORY_SCOPE_AGENT);
        }

        // h-part (chunks 16..47)
        const u16* hr = hhi + ((size_t)t * B_ + w * 16 + la) * H_ + (q << 3);
#pragma unroll
        for (int ch = 0; ch < 32; ch += 4) {
            bf16x8 h0 = *(const bf16x8*)(hr + (ch << 5));
            bf16x8 h1 = *(const bf16x8*)(hr + ((ch + 1) << 5));
            bf16x8 h2 = *(const bf16x8*)(hr + ((ch + 2) << 5));
            bf16x8 h3 = *(const bf16x8*)(hr + ((ch + 3) << 5));
            bf16x8 w0 = *(const bf16x8*)(&wlds[(size_t)((16 + ch) * 64 + lane) << 3]);
            bf16x8 w1 = *(const bf16x8*)(&wlds[(size_t)((17 + ch) * 64 + lane) << 3]);
            bf16x8 w2 = *(const bf16x8*)(&wlds[(size_t)((18 + ch) * 64 + lane) << 3]);
            bf16x8 w3 = *(const bf16x8*)(&wlds[(size_t)((19 + ch) * 64 + lane) << 3]);
            a0 = __builtin_amdgcn_mfma_f32_16x16x32_bf16(h0, w0, a0, 0, 0, 0);
            a1 = __builtin_amdgcn_mfma_f32_16x16x32_bf16(h1, w1, a1, 0, 0, 0);
            a2 = __builtin_amdgcn_mfma_f32_16x16x32_bf16(h2, w2, a2, 0, 0, 0);
            a3 = __builtin_amdgcn_mfma_f32_16x16x32_bf16(h3, w3, a3, 0, 0, 0);
        }
        f32x4 acc = (a0 + a1) + (a2 + a3);

        // per-wave transpose: C[batch q*4+r][gate-unit la] -> 4 gates per lane
#pragma unroll
        for (int r = 0; r < 4; r++) ex[w][q * 4 + r][la] = acc[r];
        float s0 = ex[w][m2][(v2 << 2) + 0];
        float s1 = ex[w][m2][(v2 << 2) + 1];
        float s2 = ex[w][m2][(v2 << 2) + 2];
        float s3 = ex[w][m2][(v2 << 2) + 3];

        float fg = sigm(s0 + bF);
        float ig = sigm(s1 + bI);
        float og = sigm(s2 + bO);
        float gg = tanhf(s3 + bG);
        c_reg = fg * c_reg + ig * gg;
        float hn = og * tanhf(c_reg);
        u16 hb = f2bf(hn);
        size_t oa = ((size_t)(t + 1) * B_ + b2) * H_ + j2;
        hhi[oa] = hb;
        hlo[oa] = f2bf(hn - bf2f(hb));

        __syncthreads();   // drains vmcnt per wave -> all h stores in L2
        if (tid == 0)      // release: wbl2 pushes block's h to L3, then count
            __hip_atomic_fetch_add(&cnt[(t << 3) + (blk & 7)], 1,
                                   __ATOMIC_RELEASE, __HIP_MEMORY_SCOPE_AGENT);
    }
}

// ---- final projection: out = H_all @ Wy^T + by (bf16 hi/lo, ~fp32 quality)
__global__ __launch_bounds__(256) void k_pred(
    const u16* __restrict__ ah, const u16* __restrict__ al,
    const u16* __restrict__ wyh, const u16* __restrict__ wyl,
    const float* __restrict__ by, float* __restrict__ out)
{
    const int tid = threadIdx.x;
    const int wv = tid >> 6;
    const int lane = tid & 63;
    const int la = lane & 15;
    const int kg = (lane >> 4) * 8;
    const int m0 = blockIdx.x * 64;
    const int n0 = blockIdx.y * 64 + wv * 16;

    const u16* bh = wyh + (size_t)(n0 + la) * H_ + kg;
    const u16* bl = wyl + (size_t)(n0 + la) * H_ + kg;

    f32x4 acc[4];
#pragma unroll
    for (int m = 0; m < 4; m++) acc[m] = (f32x4){0.f, 0.f, 0.f, 0.f};

    for (int k = 0; k < H_; k += 32) {
        bf16x8 bhh = *(const bf16x8*)(bh + k);
        bf16x8 bll = *(const bf16x8*)(bl + k);
#pragma unroll
        for (int m = 0; m < 4; m++) {
            size_t arow = (size_t)(m0 + m * 16 + la);
            bf16x8 aa  = *(const bf16x8*)(ah + arow * H_ + k + kg);
            bf16x8 aal = *(const bf16x8*)(al + arow * H_ + k + kg);
            acc[m] = __builtin_amdgcn_mfma_f32_16x16x32_bf16(aal, bhh, acc[m], 0, 0, 0);
            acc[m] = __builtin_amdgcn_mfma_f32_16x16x32_bf16(aa, bll, acc[m], 0, 0, 0);
            acc[m] = __builtin_amdgcn_mfma_f32_16x16x32_bf16(aa, bhh, acc[m], 0, 0, 0);
        }
    }

#pragma unroll
    for (int m = 0; m < 4; m++)
#pragma unroll
        for (int r = 0; r < 4; r++) {
            int row = m0 + m * 16 + (lane >> 4) * 4 + r;
            int col = n0 + la;
            out[(size_t)row * O_ + col] = acc[m][r] + by[col];
        }
}

// ---- host ------------------------------------------------------------------

extern "C" void kernel_launch(void* const* d_in, const int* in_sizes, int n_in,
                              void* d_out, int out_size, void* d_ws, size_t ws_size,
                              hipStream_t stream) {
    const float* x   = (const float*)d_in[0];
    const float* Wf  = (const float*)d_in[1];
    const float* bfv = (const float*)d_in[2];
    const float* Wi  = (const float*)d_in[3];
    const float* biv = (const float*)d_in[4];
    const float* Wo  = (const float*)d_in[5];
    const float* bov = (const float*)d_in[6];
    const float* Wg  = (const float*)d_in[7];
    const float* bgv = (const float*)d_in[8];
    const float* Wy  = (const float*)d_in[9];
    const float* by  = (const float*)d_in[10];
    float* out = (float*)d_out;

    char* ws = (char*)d_ws;
    size_t off = 0;
    auto alloc = [&](size_t bytes) {
        char* p = ws + off;
        off += (bytes + 255) & ~(size_t)255;
        return p;
    };
    u16*   Wall = (u16*)alloc((size_t)NG_ * C_ * 2);
    u16*   Wyhi = (u16*)alloc((size_t)O_ * H_ * 2);
    u16*   Wylo = (u16*)alloc((size_t)O_ * H_ * 2);
    u16*   xbf  = (u16*)alloc((size_t)S_ * B_ * I_ * 2);
    u16*   hhi  = (u16*)alloc((size_t)(S_ + 1) * B_ * H_ * 2);
    u16*   hlo  = (u16*)alloc((size_t)(S_ + 1) * B_ * H_ * 2);
    int*   cnt  = (int*)alloc((size_t)S_ * 8 * 4);

    (void)hipMemsetAsync(hhi, 0, (size_t)B_ * H_ * 2, stream);   // h(0) = 0
    (void)hipMemsetAsync(cnt, 0, (size_t)S_ * 8 * 4, stream);    // step counters

    k_pack_w <<<3072, 256, 0, stream>>>(Wf, Wi, Wo, Wg, Wall);
    k_pack_wy<<<256,  256, 0, stream>>>(Wy, Wyhi, Wylo);
    k_pack_x <<<8192, 256, 0, stream>>>(x, xbf);

    k_lstm<<<256, 256, 0, stream>>>(Wall, xbf, bfv, biv, bov, bgv, hhi, hlo, cnt);

    k_pred<<<dim3(512, 8), 256, 0, stream>>>(hhi + (size_t)B_ * H_, hlo + (size_t)B_ * H_,
                                             Wyhi, Wylo, by, out);
}

// Round 4
// 6528.925 us; speedup vs baseline: 1.6552x; 1.6552x over previous
//
#include <hip/hip_runtime.h>

#define S_ 512
#define B_ 64
#define I_ 512
#define H_ 1024
#define O_ 512
#define C_ 1536   // I_ + H_
#define NG_ 4096  // 4*H_

typedef unsigned short u16;
typedef unsigned long long u64;
typedef __attribute__((ext_vector_type(8))) short bf16x8;
typedef __attribute__((ext_vector_type(8))) unsigned short u16x8;
typedef __attribute__((ext_vector_type(4))) float f32x4;

__device__ __forceinline__ u16 f2bf(float f) {
    union { float f; unsigned int u; } v; v.f = f;
    unsigned int u = v.u;
    unsigned int r = (u + 0x7fffu + ((u >> 16) & 1u)) >> 16;
    return (u16)r;
}
__device__ __forceinline__ float bf2f(u16 h) {
    union { unsigned int u; float f; } v; v.u = ((unsigned int)h) << 16;
    return v.f;
}
__device__ __forceinline__ float sigm(float x) { return 1.0f / (1.0f + __expf(-x)); }

// bypassing (cross-XCD coherent) 16B load as two relaxed agent-scope u64 atomics:
// compiles to global_load_dwordx2 with sc-bits set -> served from MALL, never a
// stale local L1/L2 line. NO cache-maintenance instructions.
__device__ __forceinline__ bf16x8 ld_coh(const u16* p) {
    union { u64 q[2]; bf16x8 v; } u;
    u.q[0] = __hip_atomic_load((u64*)p,       __ATOMIC_RELAXED, __HIP_MEMORY_SCOPE_AGENT);
    u.q[1] = __hip_atomic_load((u64*)(p + 4), __ATOMIC_RELAXED, __HIP_MEMORY_SCOPE_AGENT);
    return u.v;
}

// ---- packing kernels -------------------------------------------------------

__global__ void k_pack_w(const float* __restrict__ Wf, const float* __restrict__ Wi,
                         const float* __restrict__ Wo, const float* __restrict__ Wg,
                         u16* __restrict__ Wall) {
    size_t i8 = ((size_t)blockIdx.x * blockDim.x + threadIdx.x) * 8;
    if (i8 >= (size_t)NG_ * C_) return;
    size_t n = i8 / C_;
    size_t k = i8 - n * C_;
    const float* Ws[4] = {Wf, Wi, Wo, Wg};
    const float* src = Ws[n >> 10] + (n & 1023) * C_ + k;
    u16x8 o;
#pragma unroll
    for (int j = 0; j < 8; j++) o[j] = f2bf(src[j]);
    *(u16x8*)(Wall + i8) = o;
}

__global__ void k_pack_wy(const float* __restrict__ Wy,
                          u16* __restrict__ hi, u16* __restrict__ lo) {
    size_t i8 = ((size_t)blockIdx.x * blockDim.x + threadIdx.x) * 8;
    if (i8 >= (size_t)O_ * H_) return;
    u16x8 oh, ol;
#pragma unroll
    for (int j = 0; j < 8; j++) {
        float v = Wy[i8 + j];
        oh[j] = f2bf(v);
        ol[j] = f2bf(v - bf2f(oh[j]));
    }
    *(u16x8*)(hi + i8) = oh;
    *(u16x8*)(lo + i8) = ol;
}

__global__ void k_pack_x(const float* __restrict__ x, u16* __restrict__ xb) {
    size_t i8 = ((size_t)blockIdx.x * blockDim.x + threadIdx.x) * 8;
    if (i8 >= (size_t)S_ * B_ * I_) return;
    u16x8 o;
#pragma unroll
    for (int j = 0; j < 8; j++) o[j] = f2bf(x[i8 + j]);
    *(u16x8*)(xb + i8) = o;
}

// ---- persistent LSTM: all 512 steps in one kernel --------------------------
// 256 blocks x 256 threads. Block owns 4 hidden units x 4 gates x full K;
// 48 KB weight slice lives in LDS for the whole sequence. Wave w owns batch
// rows [16w,16w+16): 48 chained MFMAs/step, c-state in a register.
// Cross-step coherence is HAND-ROLLED (round-1 post-mortem: agent-scope
// acquire/release fences emit buffer_inv / buffer_wbl2 whole-cache ops ->
// 97% idle). Here: h-hi travels via relaxed agent atomics (sc-bit bypass,
// write-through to MALL); ordering via per-wave s_waitcnt vmcnt(0) before a
// RELAXED memory-side fetch_add; consumers spin on bypassing loads. Zero
// cache-maintenance instructions -> x and weights stay L2-resident.
// The spin is BOUNDED (watchdog): a protocol failure produces wrong numbers
// (diagnosable) instead of a hung container.
__global__ __launch_bounds__(256, 2) void k_lstm(
    const u16* __restrict__ Wall,   // [4096][1536] bf16
    const u16* __restrict__ xbf,    // [S][64][512] bf16
    const float* __restrict__ bfv, const float* __restrict__ biv,
    const float* __restrict__ bov, const float* __restrict__ bgv,
    u16* __restrict__ hhi,          // [S+1][64][1024] bf16
    u16* __restrict__ hlo,          // [S+1][64][1024] bf16 residual
    int* __restrict__ cnt)          // [S][8] step-completion counters
{
    __shared__ __align__(16) u16 wlds[48 * 64 * 8];  // 48 KB: [chunk][lane][8]
    __shared__ float ex[4][16][17];                  // per-wave gate exchange
    __shared__ __align__(8) u16 hxh[64][4];          // h-hi staging [batch][unit]
    __shared__ __align__(8) u16 hxl[64][4];          // h-lo staging

    const int tid = threadIdx.x;
    const int w = tid >> 6;          // wave -> batch rows [16w,16w+16)
    const int lane = tid & 63;
    const int la = lane & 15;        // A row (batch) / B row (gate-unit)
    const int q = lane >> 4;         // k sub-offset group / C row group
    const int blk = blockIdx.x;      // owns hidden units [4*blk, 4*blk+4)

    // ---- stage the weight slice into LDS, MFMA fragment order ----
    {
        const int p = tid >> 4;
        const int g = p & 3, v = p >> 2;
        const u16* wrow = Wall + (size_t)(g * H_ + blk * 4 + v) * C_;
        const int kb = tid & 15;
#pragma unroll
        for (int i = 0; i < 12; i++) {
            int k8 = kb + (i << 4);                      // 0..191
            bf16x8 wv = *(const bf16x8*)(wrow + (k8 << 3));
            int off16 = ((k8 >> 2) << 6) + ((k8 & 3) << 4) + p;
            *(bf16x8*)(&wlds[(size_t)off16 << 3]) = wv;
        }
    }

    // epilogue ownership: lane -> (batch b2, unit j2); c lives in a register
    const int m2 = lane & 15;
    const int v2 = lane >> 4;
    const int b2 = w * 16 + m2;
    const int j2 = blk * 4 + v2;
    const float bF = bfv[j2], bI = biv[j2], bO = bov[j2], bG = bgv[j2];
    float c_reg = 0.f;

    __syncthreads();   // wlds ready (cross-wave)

    for (int t = 0; t < S_; t++) {
        const u16* xr = xbf + ((size_t)t * B_ + w * 16 + la) * I_ + (q << 3);
        f32x4 a0 = (f32x4){0.f,0.f,0.f,0.f};
        f32x4 a1 = (f32x4){0.f,0.f,0.f,0.f};
        f32x4 a2 = (f32x4){0.f,0.f,0.f,0.f};
        f32x4 a3 = (f32x4){0.f,0.f,0.f,0.f};

        // x-part (chunks 0..15): independent of h -> runs before the sync.
        // Plain cached loads: x stays L2-resident (no invalidates anywhere).
#pragma unroll
        for (int ch = 0; ch < 16; ch += 4) {
            bf16x8 x0 = *(const bf16x8*)(xr + (ch << 5));
            bf16x8 x1 = *(const bf16x8*)(xr + ((ch + 1) << 5));
            bf16x8 x2 = *(const bf16x8*)(xr + ((ch + 2) << 5));
            bf16x8 x3 = *(const bf16x8*)(xr + ((ch + 3) << 5));
            bf16x8 w0 = *(const bf16x8*)(&wlds[(size_t)((ch    ) * 64 + lane) << 3]);
            bf16x8 w1 = *(const bf16x8*)(&wlds[(size_t)((ch + 1) * 64 + lane) << 3]);
            bf16x8 w2 = *(const bf16x8*)(&wlds[(size_t)((ch + 2) * 64 + lane) << 3]);
            bf16x8 w3 = *(const bf16x8*)(&wlds[(size_t)((ch + 3) * 64 + lane) << 3]);
            a0 = __builtin_amdgcn_mfma_f32_16x16x32_bf16(x0, w0, a0, 0, 0, 0);
            a1 = __builtin_amdgcn_mfma_f32_16x16x32_bf16(x1, w1, a1, 0, 0, 0);
            a2 = __builtin_amdgcn_mfma_f32_16x16x32_bf16(x2, w2, a2, 0, 0, 0);
            a3 = __builtin_amdgcn_mfma_f32_16x16x32_bf16(x3, w3, a3, 0, 0, 0);
        }

        // wait for h(t): all 256 blocks finished step t-1 (tid 0 polls with
        // bypassing loads; no fences, no cache maintenance). Bounded spin:
        // legit wait is <~50 polls; 16K polls (~6 ms) means protocol failure
        // -> proceed (wrong result, diagnosable) instead of hanging the box.
        if (t > 0) {
            if (tid == 0) {
                const u64* cl = (const u64*)(cnt + ((t - 1) << 3));
                int guard = 0;
                for (;;) {
                    u64 s0 = __hip_atomic_load((u64*)(cl + 0), __ATOMIC_RELAXED, __HIP_MEMORY_SCOPE_AGENT);
                    u64 s1 = __hip_atomic_load((u64*)(cl + 1), __ATOMIC_RELAXED, __HIP_MEMORY_SCOPE_AGENT);
                    u64 s2 = __hip_atomic_load((u64*)(cl + 2), __ATOMIC_RELAXED, __HIP_MEMORY_SCOPE_AGENT);
                    u64 s3 = __hip_atomic_load((u64*)(cl + 3), __ATOMIC_RELAXED, __HIP_MEMORY_SCOPE_AGENT);
                    u64 s = s0 + s1 + s2 + s3;
                    s = (s & 0xffffffffull) + (s >> 32);
                    if (s == 256) break;
                    if (++guard > (1 << 14)) break;   // watchdog
                    __builtin_amdgcn_s_sleep(1);
                }
            }
            __syncthreads();
            asm volatile("" ::: "memory");   // compiler fence: keep h loads below
        }

        // h-part (chunks 16..47), bypassing loads (fresh from MALL)
        const u16* hr = hhi + ((size_t)t * B_ + w * 16 + la) * H_ + (q << 3);
#pragma unroll
        for (int ch = 0; ch < 32; ch += 4) {
            bf16x8 h0 = ld_coh(hr + (ch << 5));
            bf16x8 h1 = ld_coh(hr + ((ch + 1) << 5));
            bf16x8 h2 = ld_coh(hr + ((ch + 2) << 5));
            bf16x8 h3 = ld_coh(hr + ((ch + 3) << 5));
            bf16x8 w0 = *(const bf16x8*)(&wlds[(size_t)((16 + ch) * 64 + lane) << 3]);
            bf16x8 w1 = *(const bf16x8*)(&wlds[(size_t)((17 + ch) * 64 + lane) << 3]);
            bf16x8 w2 = *(const bf16x8*)(&wlds[(size_t)((18 + ch) * 64 + lane) << 3]);
            bf16x8 w3 = *(const bf16x8*)(&wlds[(size_t)((19 + ch) * 64 + lane) << 3]);
            a0 = __builtin_amdgcn_mfma_f32_16x16x32_bf16(h0, w0, a0, 0, 0, 0);
            a1 = __builtin_amdgcn_mfma_f32_16x16x32_bf16(h1, w1, a1, 0, 0, 0);
            a2 = __builtin_amdgcn_mfma_f32_16x16x32_bf16(h2, w2, a2, 0, 0, 0);
            a3 = __builtin_amdgcn_mfma_f32_16x16x32_bf16(h3, w3, a3, 0, 0, 0);
        }
        f32x4 acc = (a0 + a1) + (a2 + a3);

        // per-wave transpose: C[batch q*4+r][gate-unit la] -> 4 gates per lane
#pragma unroll
        for (int r = 0; r < 4; r++) ex[w][q * 4 + r][la] = acc[r];
        float s0 = ex[w][m2][(v2 << 2) + 0];
        float s1 = ex[w][m2][(v2 << 2) + 1];
        float s2 = ex[w][m2][(v2 << 2) + 2];
        float s3 = ex[w][m2][(v2 << 2) + 3];

        float fg = sigm(s0 + bF);
        float ig = sigm(s1 + bI);
        float og = sigm(s2 + bO);
        float gg = tanhf(s3 + bG);
        c_reg = fg * c_reg + ig * gg;
        float hn = og * tanhf(c_reg);
        u16 hb = f2bf(hn);
        hxh[b2][v2] = hb;
        hxl[b2][v2] = f2bf(hn - bf2f(hb));

        __syncthreads();   // h staging complete

        // coalesced h writeout: wave 0, one 8B store per batch row.
        // hi: write-through agent atomics (MALL-visible); lo: plain (only
        // k_pred reads it, after a kernel boundary).
        if (tid < 64) {
            u64 hv = *(const u64*)&hxh[tid][0];
            u64 lv = *(const u64*)&hxl[tid][0];
            size_t ro = ((size_t)(t + 1) * B_ + tid) * H_ + (size_t)blk * 4;
            __hip_atomic_store((u64*)(hhi + ro), hv, __ATOMIC_RELAXED, __HIP_MEMORY_SCOPE_AGENT);
            *(u64*)(hlo + ro) = lv;
        }
        if (tid == 0) {
            // all step-t h stores were issued by THIS wave -> vmcnt covers them
            asm volatile("s_waitcnt vmcnt(0)" ::: "memory");
            __hip_atomic_fetch_add(&cnt[(t << 3) + (blk & 7)], 1,
                                   __ATOMIC_RELAXED, __HIP_MEMORY_SCOPE_AGENT);
        }
        // no trailing barrier needed: nobody touches hxh/hxl until after the
        // next step's spin barrier, which wave 0 only reaches past this point.
    }
}

// ---- final projection: out = H_all @ Wy^T + by (bf16 hi/lo, ~fp32 quality)
__global__ __launch_bounds__(256) void k_pred(
    const u16* __restrict__ ah, const u16* __restrict__ al,
    const u16* __restrict__ wyh, const u16* __restrict__ wyl,
    const float* __restrict__ by, float* __restrict__ out)
{
    const int tid = threadIdx.x;
    const int wv = tid >> 6;
    const int lane = tid & 63;
    const int la = lane & 15;
    const int kg = (lane >> 4) * 8;
    const int m0 = blockIdx.x * 64;
    const int n0 = blockIdx.y * 64 + wv * 16;

    const u16* bh = wyh + (size_t)(n0 + la) * H_ + kg;
    const u16* bl = wyl + (size_t)(n0 + la) * H_ + kg;

    f32x4 acc[4];
#pragma unroll
    for (int m = 0; m < 4; m++) acc[m] = (f32x4){0.f, 0.f, 0.f, 0.f};

    for (int k = 0; k < H_; k += 32) {
        bf16x8 bhh = *(const bf16x8*)(bh + k);
        bf16x8 bll = *(const bf16x8*)(bl + k);
#pragma unroll
        for (int m = 0; m < 4; m++) {
            size_t arow = (size_t)(m0 + m * 16 + la);
            bf16x8 aa  = *(const bf16x8*)(ah + arow * H_ + k + kg);
            bf16x8 aal = *(const bf16x8*)(al + arow * H_ + k + kg);
            acc[m] = __builtin_amdgcn_mfma_f32_16x16x32_bf16(aal, bhh, acc[m], 0, 0, 0);
            acc[m] = __builtin_amdgcn_mfma_f32_16x16x32_bf16(aa, bll, acc[m], 0, 0, 0);
            acc[m] = __builtin_amdgcn_mfma_f32_16x16x32_bf16(aa, bhh, acc[m], 0, 0, 0);
        }
    }

#pragma unroll
    for (int m = 0; m < 4; m++)
#pragma unroll
        for (int r = 0; r < 4; r++) {
            int row = m0 + m * 16 + (lane >> 4) * 4 + r;
            int col = n0 + la;
            out[(size_t)row * O_ + col] = acc[m][r] + by[col];
        }
}

// ---- host ------------------------------------------------------------------

extern "C" void kernel_launch(void* const* d_in, const int* in_sizes, int n_in,
                              void* d_out, int out_size, void* d_ws, size_t ws_size,
                              hipStream_t stream) {
    const float* x   = (const float*)d_in[0];
    const float* Wf  = (const float*)d_in[1];
    const float* bfv = (const float*)d_in[2];
    const float* Wi  = (const float*)d_in[3];
    const float* biv = (const float*)d_in[4];
    const float* Wo  = (const float*)d_in[5];
    const float* bov = (const float*)d_in[6];
    const float* Wg  = (const float*)d_in[7];
    const float* bgv = (const float*)d_in[8];
    const float* Wy  = (const float*)d_in[9];
    const float* by  = (const float*)d_in[10];
    float* out = (float*)d_out;

    char* ws = (char*)d_ws;
    size_t off = 0;
    auto alloc = [&](size_t bytes) {
        char* p = ws + off;
        off += (bytes + 255) & ~(size_t)255;
        return p;
    };
    u16*   Wall = (u16*)alloc((size_t)NG_ * C_ * 2);
    u16*   Wyhi = (u16*)alloc((size_t)O_ * H_ * 2);
    u16*   Wylo = (u16*)alloc((size_t)O_ * H_ * 2);
    u16*   xbf  = (u16*)alloc((size_t)S_ * B_ * I_ * 2);
    u16*   hhi  = (u16*)alloc((size_t)(S_ + 1) * B_ * H_ * 2);
    u16*   hlo  = (u16*)alloc((size_t)(S_ + 1) * B_ * H_ * 2);
    int*   cnt  = (int*)alloc((size_t)S_ * 8 * 4);

    (void)hipMemsetAsync(hhi, 0, (size_t)B_ * H_ * 2, stream);   // h(0) = 0
    (void)hipMemsetAsync(cnt, 0, (size_t)S_ * 8 * 4, stream);    // step counters

    k_pack_w <<<3072, 256, 0, stream>>>(Wf, Wi, Wo, Wg, Wall);
    k_pack_wy<<<256,  256, 0, stream>>>(Wy, Wyhi, Wylo);
    k_pack_x <<<8192, 256, 0, stream>>>(x, xbf);

    k_lstm<<<256, 256, 0, stream>>>(Wall, xbf, bfv, biv, bov, bgv, hhi, hlo, cnt);

    k_pred<<<dim3(512, 8), 256, 0, stream>>>(hhi + (size_t)B_ * H_, hlo + (size_t)B_ * H_,
                                             Wyhi, Wylo, by, out);
}

// Round 5
// 4862.437 us; speedup vs baseline: 2.2225x; 1.3427x over previous
//
#include <hip/hip_runtime.h>

#define S_ 512
#define B_ 64
#define I_ 512
#define H_ 1024
#define O_ 512
#define C_ 1536   // I_ + H_
#define NG_ 4096  // 4*H_

typedef unsigned short u16;
typedef unsigned long long u64;
typedef __attribute__((ext_vector_type(8))) short bf16x8;
typedef __attribute__((ext_vector_type(8))) unsigned short u16x8;
typedef __attribute__((ext_vector_type(4))) float f32x4;

__device__ __forceinline__ u16 f2bf(float f) {
    union { float f; unsigned int u; } v; v.f = f;
    unsigned int u = v.u;
    unsigned int r = (u + 0x7fffu + ((u >> 16) & 1u)) >> 16;
    return (u16)r;
}
__device__ __forceinline__ float bf2f(u16 h) {
    union { unsigned int u; float f; } v; v.u = ((unsigned int)h) << 16;
    return v.f;
}
__device__ __forceinline__ float sigm(float x) { return 1.0f / (1.0f + __expf(-x)); }

// ---- packing kernels -------------------------------------------------------

__global__ void k_pack_w(const float* __restrict__ Wf, const float* __restrict__ Wi,
                         const float* __restrict__ Wo, const float* __restrict__ Wg,
                         u16* __restrict__ Wall) {
    size_t i8 = ((size_t)blockIdx.x * blockDim.x + threadIdx.x) * 8;
    if (i8 >= (size_t)NG_ * C_) return;
    size_t n = i8 / C_;
    size_t k = i8 - n * C_;
    const float* Ws[4] = {Wf, Wi, Wo, Wg};
    const float* src = Ws[n >> 10] + (n & 1023) * C_ + k;
    u16x8 o;
#pragma unroll
    for (int j = 0; j < 8; j++) o[j] = f2bf(src[j]);
    *(u16x8*)(Wall + i8) = o;
}

__global__ void k_pack_wy(const float* __restrict__ Wy,
                          u16* __restrict__ hi, u16* __restrict__ lo) {
    size_t i8 = ((size_t)blockIdx.x * blockDim.x + threadIdx.x) * 8;
    if (i8 >= (size_t)O_ * H_) return;
    u16x8 oh, ol;
#pragma unroll
    for (int j = 0; j < 8; j++) {
        float v = Wy[i8 + j];
        oh[j] = f2bf(v);
        ol[j] = f2bf(v - bf2f(oh[j]));
    }
    *(u16x8*)(hi + i8) = oh;
    *(u16x8*)(lo + i8) = ol;
}

__global__ void k_pack_x(const float* __restrict__ x, u16* __restrict__ xb) {
    size_t i8 = ((size_t)blockIdx.x * blockDim.x + threadIdx.x) * 8;
    if (i8 >= (size_t)S_ * B_ * I_) return;
    u16x8 o;
#pragma unroll
    for (int j = 0; j < 8; j++) o[j] = f2bf(x[i8 + j]);
    *(u16x8*)(xb + i8) = o;
}

// ---- persistent LSTM: all 512 steps in one kernel --------------------------
// 256 blocks x 256 threads. Block owns 4 hidden units x 4 gates x full K;
// 48 KB weight slice lives in LDS for the whole sequence. Wave w owns batch
// rows [16w,16w+16): 48 chained MFMAs/step, c-state in a register.
// Coherence protocol (round-4 post-mortem): h-hi is WRITTEN with sc-bit
// write-through atomics (reaches MALL before the flag) but READ with PLAIN
// CACHED loads. Round 4 used atomic u64 loads for h: 4M 8-byte atomic-pipe
// transactions/step serialized on TCC (~11.5 us/step, all pipes <3% busy).
// Plain reads are safe: each h(t+1) line is written once (write-through) and
// only read strictly after the flag -> no reader cache can hold a stale copy
// (demand-fill caches; dispatch-boundary fences cover cross-kernel reuse,
// as already proven by k_pack_w -> k_lstm plain-load consumption).
// Release: per-wave s_waitcnt vmcnt(0) then RELAXED memory-side fetch_add.
// Acquire: tid0 polls with bypassing atomic loads. Zero cache-maintenance
// instructions anywhere. Spin is BOUNDED (watchdog): protocol failure gives
// wrong numbers (diagnosable), not a hung container.
__global__ __launch_bounds__(256, 2) void k_lstm(
    const u16* __restrict__ Wall,   // [4096][1536] bf16
    const u16* __restrict__ xbf,    // [S][64][512] bf16
    const float* __restrict__ bfv, const float* __restrict__ biv,
    const float* __restrict__ bov, const float* __restrict__ bgv,
    u16* __restrict__ hhi,          // [S+1][64][1024] bf16
    u16* __restrict__ hlo,          // [S+1][64][1024] bf16 residual
    int* __restrict__ cnt)          // [S][8] step-completion counters
{
    __shared__ __align__(16) u16 wlds[48 * 64 * 8];  // 48 KB: [chunk][lane][8]
    __shared__ float ex[4][16][17];                  // per-wave gate exchange
    __shared__ __align__(8) u16 hxh[64][4];          // h-hi staging [batch][unit]
    __shared__ __align__(8) u16 hxl[64][4];          // h-lo staging

    const int tid = threadIdx.x;
    const int w = tid >> 6;          // wave -> batch rows [16w,16w+16)
    const int lane = tid & 63;
    const int la = lane & 15;        // A row (batch) / B row (gate-unit)
    const int q = lane >> 4;         // k sub-offset group / C row group
    const int blk = blockIdx.x;      // owns hidden units [4*blk, 4*blk+4)

    // ---- stage the weight slice into LDS, MFMA fragment order ----
    {
        const int p = tid >> 4;
        const int g = p & 3, v = p >> 2;
        const u16* wrow = Wall + (size_t)(g * H_ + blk * 4 + v) * C_;
        const int kb = tid & 15;
#pragma unroll
        for (int i = 0; i < 12; i++) {
            int k8 = kb + (i << 4);                      // 0..191
            bf16x8 wv = *(const bf16x8*)(wrow + (k8 << 3));
            int off16 = ((k8 >> 2) << 6) + ((k8 & 3) << 4) + p;
            *(bf16x8*)(&wlds[(size_t)off16 << 3]) = wv;
        }
    }

    // epilogue ownership: lane -> (batch b2, unit j2); c lives in a register
    const int m2 = lane & 15;
    const int v2 = lane >> 4;
    const int b2 = w * 16 + m2;
    const int j2 = blk * 4 + v2;
    const float bF = bfv[j2], bI = biv[j2], bO = bov[j2], bG = bgv[j2];
    float c_reg = 0.f;

    __syncthreads();   // wlds ready (cross-wave)

    for (int t = 0; t < S_; t++) {
        const u16* xr = xbf + ((size_t)t * B_ + w * 16 + la) * I_ + (q << 3);
        f32x4 a0 = (f32x4){0.f,0.f,0.f,0.f};
        f32x4 a1 = (f32x4){0.f,0.f,0.f,0.f};
        f32x4 a2 = (f32x4){0.f,0.f,0.f,0.f};
        f32x4 a3 = (f32x4){0.f,0.f,0.f,0.f};

        // x-part (chunks 0..15): independent of h -> runs before the sync.
#pragma unroll
        for (int ch = 0; ch < 16; ch += 4) {
            bf16x8 x0 = *(const bf16x8*)(xr + (ch << 5));
            bf16x8 x1 = *(const bf16x8*)(xr + ((ch + 1) << 5));
            bf16x8 x2 = *(const bf16x8*)(xr + ((ch + 2) << 5));
            bf16x8 x3 = *(const bf16x8*)(xr + ((ch + 3) << 5));
            bf16x8 w0 = *(const bf16x8*)(&wlds[(size_t)((ch    ) * 64 + lane) << 3]);
            bf16x8 w1 = *(const bf16x8*)(&wlds[(size_t)((ch + 1) * 64 + lane) << 3]);
            bf16x8 w2 = *(const bf16x8*)(&wlds[(size_t)((ch + 2) * 64 + lane) << 3]);
            bf16x8 w3 = *(const bf16x8*)(&wlds[(size_t)((ch + 3) * 64 + lane) << 3]);
            a0 = __builtin_amdgcn_mfma_f32_16x16x32_bf16(x0, w0, a0, 0, 0, 0);
            a1 = __builtin_amdgcn_mfma_f32_16x16x32_bf16(x1, w1, a1, 0, 0, 0);
            a2 = __builtin_amdgcn_mfma_f32_16x16x32_bf16(x2, w2, a2, 0, 0, 0);
            a3 = __builtin_amdgcn_mfma_f32_16x16x32_bf16(x3, w3, a3, 0, 0, 0);
        }

        // wait for h(t): all 256 blocks finished step t-1 (tid 0 polls with
        // bypassing loads). Bounded spin: legit wait is <~50 polls; 16K polls
        // means protocol failure -> proceed (diagnosable) instead of hanging.
        if (t > 0) {
            if (tid == 0) {
                const u64* cl = (const u64*)(cnt + ((t - 1) << 3));
                int guard = 0;
                for (;;) {
                    u64 s0 = __hip_atomic_load((u64*)(cl + 0), __ATOMIC_RELAXED, __HIP_MEMORY_SCOPE_AGENT);
                    u64 s1 = __hip_atomic_load((u64*)(cl + 1), __ATOMIC_RELAXED, __HIP_MEMORY_SCOPE_AGENT);
                    u64 s2 = __hip_atomic_load((u64*)(cl + 2), __ATOMIC_RELAXED, __HIP_MEMORY_SCOPE_AGENT);
                    u64 s3 = __hip_atomic_load((u64*)(cl + 3), __ATOMIC_RELAXED, __HIP_MEMORY_SCOPE_AGENT);
                    u64 s = s0 + s1 + s2 + s3;
                    s = (s & 0xffffffffull) + (s >> 32);
                    if (s == 256) break;
                    if (++guard > (1 << 14)) break;   // watchdog
                    __builtin_amdgcn_s_sleep(1);
                }
            }
            __syncthreads();
            asm volatile("" ::: "memory");   // compiler fence: keep h loads below
        }

        // h-part (chunks 16..47): PLAIN CACHED dwordx4 loads (the round-4
        // atomic-load path serialized on the TCC atomic pipe). Lines are
        // freshly written this step and never previously cached -> safe.
        const u16* hr = hhi + ((size_t)t * B_ + w * 16 + la) * H_ + (q << 3);
#pragma unroll
        for (int ch = 0; ch < 32; ch += 4) {
            bf16x8 h0 = *(const bf16x8*)(hr + (ch << 5));
            bf16x8 h1 = *(const bf16x8*)(hr + ((ch + 1) << 5));
            bf16x8 h2 = *(const bf16x8*)(hr + ((ch + 2) << 5));
            bf16x8 h3 = *(const bf16x8*)(hr + ((ch + 3) << 5));
            bf16x8 w0 = *(const bf16x8*)(&wlds[(size_t)((16 + ch) * 64 + lane) << 3]);
            bf16x8 w1 = *(const bf16x8*)(&wlds[(size_t)((17 + ch) * 64 + lane) << 3]);
            bf16x8 w2 = *(const bf16x8*)(&wlds[(size_t)((18 + ch) * 64 + lane) << 3]);
            bf16x8 w3 = *(const bf16x8*)(&wlds[(size_t)((19 + ch) * 64 + lane) << 3]);
            a0 = __builtin_amdgcn_mfma_f32_16x16x32_bf16(h0, w0, a0, 0, 0, 0);
            a1 = __builtin_amdgcn_mfma_f32_16x16x32_bf16(h1, w1, a1, 0, 0, 0);
            a2 = __builtin_amdgcn_mfma_f32_16x16x32_bf16(h2, w2, a2, 0, 0, 0);
            a3 = __builtin_amdgcn_mfma_f32_16x16x32_bf16(h3, w3, a3, 0, 0, 0);
        }
        f32x4 acc = (a0 + a1) + (a2 + a3);

        // per-wave transpose: C[batch q*4+r][gate-unit la] -> 4 gates per lane
#pragma unroll
        for (int r = 0; r < 4; r++) ex[w][q * 4 + r][la] = acc[r];
        float s0 = ex[w][m2][(v2 << 2) + 0];
        float s1 = ex[w][m2][(v2 << 2) + 1];
        float s2 = ex[w][m2][(v2 << 2) + 2];
        float s3 = ex[w][m2][(v2 << 2) + 3];

        float fg = sigm(s0 + bF);
        float ig = sigm(s1 + bI);
        float og = sigm(s2 + bO);
        float gg = tanhf(s3 + bG);
        c_reg = fg * c_reg + ig * gg;
        float hn = og * tanhf(c_reg);
        u16 hb = f2bf(hn);
        hxh[b2][v2] = hb;
        hxl[b2][v2] = f2bf(hn - bf2f(hb));

        __syncthreads();   // h staging complete

        // coalesced h writeout: wave 0, one 8B store per batch row.
        // hi: write-through agent atomics (MALL-visible before the flag);
        // lo: plain (only k_pred reads it, after a kernel boundary).
        if (tid < 64) {
            u64 hv = *(const u64*)&hxh[tid][0];
            u64 lv = *(const u64*)&hxl[tid][0];
            size_t ro = ((size_t)(t + 1) * B_ + tid) * H_ + (size_t)blk * 4;
            __hip_atomic_store((u64*)(hhi + ro), hv, __ATOMIC_RELAXED, __HIP_MEMORY_SCOPE_AGENT);
            *(u64*)(hlo + ro) = lv;
        }
        if (tid == 0) {
            // all step-t h stores were issued by THIS wave -> vmcnt covers them
            asm volatile("s_waitcnt vmcnt(0)" ::: "memory");
            __hip_atomic_fetch_add(&cnt[(t << 3) + (blk & 7)], 1,
                                   __ATOMIC_RELAXED, __HIP_MEMORY_SCOPE_AGENT);
        }
        // no trailing barrier needed: nobody touches hxh/hxl until after the
        // next step's spin barrier, which wave 0 only reaches past this point.
    }
}

// ---- final projection: out = H_all @ Wy^T + by (bf16 hi/lo, ~fp32 quality)
__global__ __launch_bounds__(256) void k_pred(
    const u16* __restrict__ ah, const u16* __restrict__ al,
    const u16* __restrict__ wyh, const u16* __restrict__ wyl,
    const float* __restrict__ by, float* __restrict__ out)
{
    const int tid = threadIdx.x;
    const int wv = tid >> 6;
    const int lane = tid & 63;
    const int la = lane & 15;
    const int kg = (lane >> 4) * 8;
    const int m0 = blockIdx.x * 64;
    const int n0 = blockIdx.y * 64 + wv * 16;

    const u16* bh = wyh + (size_t)(n0 + la) * H_ + kg;
    const u16* bl = wyl + (size_t)(n0 + la) * H_ + kg;

    f32x4 acc[4];
#pragma unroll
    for (int m = 0; m < 4; m++) acc[m] = (f32x4){0.f, 0.f, 0.f, 0.f};

    for (int k = 0; k < H_; k += 32) {
        bf16x8 bhh = *(const bf16x8*)(bh + k);
        bf16x8 bll = *(const bf16x8*)(bl + k);
#pragma unroll
        for (int m = 0; m < 4; m++) {
            size_t arow = (size_t)(m0 + m * 16 + la);
            bf16x8 aa  = *(const bf16x8*)(ah + arow * H_ + k + kg);
            bf16x8 aal = *(const bf16x8*)(al + arow * H_ + k + kg);
            acc[m] = __builtin_amdgcn_mfma_f32_16x16x32_bf16(aal, bhh, acc[m], 0, 0, 0);
            acc[m] = __builtin_amdgcn_mfma_f32_16x16x32_bf16(aa, bll, acc[m], 0, 0, 0);
            acc[m] = __builtin_amdgcn_mfma_f32_16x16x32_bf16(aa, bhh, acc[m], 0, 0, 0);
        }
    }

#pragma unroll
    for (int m = 0; m < 4; m++)
#pragma unroll
        for (int r = 0; r < 4; r++) {
            int row = m0 + m * 16 + (lane >> 4) * 4 + r;
            int col = n0 + la;
            out[(size_t)row * O_ + col] = acc[m][r] + by[col];
        }
}

// ---- host ------------------------------------------------------------------

extern "C" void kernel_launch(void* const* d_in, const int* in_sizes, int n_in,
                              void* d_out, int out_size, void* d_ws, size_t ws_size,
                              hipStream_t stream) {
    const float* x   = (const float*)d_in[0];
    const float* Wf  = (const float*)d_in[1];
    const float* bfv = (const float*)d_in[2];
    const float* Wi  = (const float*)d_in[3];
    const float* biv = (const float*)d_in[4];
    const float* Wo  = (const float*)d_in[5];
    const float* bov = (const float*)d_in[6];
    const float* Wg  = (const float*)d_in[7];
    const float* bgv = (const float*)d_in[8];
    const float* Wy  = (const float*)d_in[9];
    const float* by  = (const float*)d_in[10];
    float* out = (float*)d_out;

    char* ws = (char*)d_ws;
    size_t off = 0;
    auto alloc = [&](size_t bytes) {
        char* p = ws + off;
        off += (bytes + 255) & ~(size_t)255;
        return p;
    };
    u16*   Wall = (u16*)alloc((size_t)NG_ * C_ * 2);
    u16*   Wyhi = (u16*)alloc((size_t)O_ * H_ * 2);
    u16*   Wylo = (u16*)alloc((size_t)O_ * H_ * 2);
    u16*   xbf  = (u16*)alloc((size_t)S_ * B_ * I_ * 2);
    u16*   hhi  = (u16*)alloc((size_t)(S_ + 1) * B_ * H_ * 2);
    u16*   hlo  = (u16*)alloc((size_t)(S_ + 1) * B_ * H_ * 2);
    int*   cnt  = (int*)alloc((size_t)S_ * 8 * 4);

    (void)hipMemsetAsync(hhi, 0, (size_t)B_ * H_ * 2, stream);   // h(0) = 0
    (void)hipMemsetAsync(cnt, 0, (size_t)S_ * 8 * 4, stream);    // step counters

    k_pack_w <<<3072, 256, 0, stream>>>(Wf, Wi, Wo, Wg, Wall);
    k_pack_wy<<<256,  256, 0, stream>>>(Wy, Wyhi, Wylo);
    k_pack_x <<<8192, 256, 0, stream>>>(x, xbf);

    k_lstm<<<256, 256, 0, stream>>>(Wall, xbf, bfv, biv, bov, bgv, hhi, hlo, cnt);

    k_pred<<<dim3(512, 8), 256, 0, stream>>>(hhi + (size_t)B_ * H_, hlo + (size_t)B_ * H_,
                                             Wyhi, Wylo, by, out);
}

// Round 6
// 4849.681 us; speedup vs baseline: 2.2284x; 1.0026x over previous
//
#include <hip/hip_runtime.h>

#define S_ 512
#define B_ 64
#define I_ 512
#define H_ 1024
#define O_ 512
#define C_ 1536   // I_ + H_
#define NG_ 4096  // 4*H_

typedef unsigned short u16;
typedef unsigned long long u64;
typedef __attribute__((ext_vector_type(8))) short bf16x8;
typedef __attribute__((ext_vector_type(8))) unsigned short u16x8;
typedef __attribute__((ext_vector_type(4))) float f32x4;

__device__ __forceinline__ u16 f2bf(float f) {
    union { float f; unsigned int u; } v; v.f = f;
    unsigned int u = v.u;
    unsigned int r = (u + 0x7fffu + ((u >> 16) & 1u)) >> 16;
    return (u16)r;
}
__device__ __forceinline__ float bf2f(u16 h) {
    union { unsigned int u; float f; } v; v.u = ((unsigned int)h) << 16;
    return v.f;
}
__device__ __forceinline__ float sigm(float x) { return 1.0f / (1.0f + __expf(-x)); }

// ---- packing kernels -------------------------------------------------------

__global__ void k_pack_w(const float* __restrict__ Wf, const float* __restrict__ Wi,
                         const float* __restrict__ Wo, const float* __restrict__ Wg,
                         u16* __restrict__ Wall) {
    size_t i8 = ((size_t)blockIdx.x * blockDim.x + threadIdx.x) * 8;
    if (i8 >= (size_t)NG_ * C_) return;
    size_t n = i8 / C_;
    size_t k = i8 - n * C_;
    const float* Ws[4] = {Wf, Wi, Wo, Wg};
    const float* src = Ws[n >> 10] + (n & 1023) * C_ + k;
    u16x8 o;
#pragma unroll
    for (int j = 0; j < 8; j++) o[j] = f2bf(src[j]);
    *(u16x8*)(Wall + i8) = o;
}

__global__ void k_pack_wy(const float* __restrict__ Wy,
                          u16* __restrict__ hi, u16* __restrict__ lo) {
    size_t i8 = ((size_t)blockIdx.x * blockDim.x + threadIdx.x) * 8;
    if (i8 >= (size_t)O_ * H_) return;
    u16x8 oh, ol;
#pragma unroll
    for (int j = 0; j < 8; j++) {
        float v = Wy[i8 + j];
        oh[j] = f2bf(v);
        ol[j] = f2bf(v - bf2f(oh[j]));
    }
    *(u16x8*)(hi + i8) = oh;
    *(u16x8*)(lo + i8) = ol;
}

__global__ void k_pack_x(const float* __restrict__ x, u16* __restrict__ xb) {
    size_t i8 = ((size_t)blockIdx.x * blockDim.x + threadIdx.x) * 8;
    if (i8 >= (size_t)S_ * B_ * I_) return;
    u16x8 o;
#pragma unroll
    for (int j = 0; j < 8; j++) o[j] = f2bf(x[i8 + j]);
    *(u16x8*)(xb + i8) = o;
}

// ---- persistent LSTM: all 512 steps in one kernel --------------------------
// 256 blocks x 256 threads, 1 block/CU (grid==CU count -> always co-resident).
// Block owns 4 hidden units x 4 gates x full K; 48 KB weights in LDS for the
// whole sequence. Wave w owns batch rows [16w,16w+16): 48 MFMAs/step,
// c-state in a register.
// Round-5 post-mortem: 8.2 us/step with all pipes <4% busy = LATENCY chain.
// VGPR_Count was 68 -> the 32 h-loads ran as ~8 serial MALL round trips.
// This round: (1) prefetch ALL 32 h-chunks into registers (hb[32], fully
// unrolled) before any MFMA -> one round trip; __launch_bounds__(256,1)
// lifts the VGPR cap. (2) per-wave spin (lane0 polls) replaces tid0-spin +
// block barrier. Coherence protocol unchanged (proven r5): h-hi written with
// sc-bit write-through atomics, read with plain cached loads; release =
// per-wave vmcnt(0) then relaxed fetch_add; zero cache-maintenance ops.
// Spin is BOUNDED (watchdog): protocol failure -> wrong numbers, not a hang.
__global__ __launch_bounds__(256, 1) void k_lstm(
    const u16* __restrict__ Wall,   // [4096][1536] bf16
    const u16* __restrict__ xbf,    // [S][64][512] bf16
    const float* __restrict__ bfv, const float* __restrict__ biv,
    const float* __restrict__ bov, const float* __restrict__ bgv,
    u16* __restrict__ hhi,          // [S+1][64][1024] bf16
    u16* __restrict__ hlo,          // [S+1][64][1024] bf16 residual
    int* __restrict__ cnt)          // [S][8] step-completion counters
{
    __shared__ __align__(16) u16 wlds[48 * 64 * 8];  // 48 KB: [chunk][lane][8]
    __shared__ float ex[4][16][17];                  // per-wave gate exchange
    __shared__ __align__(8) u16 hxh[64][4];          // h-hi staging [batch][unit]
    __shared__ __align__(8) u16 hxl[64][4];          // h-lo staging

    const int tid = threadIdx.x;
    const int w = tid >> 6;          // wave -> batch rows [16w,16w+16)
    const int lane = tid & 63;
    const int la = lane & 15;        // A row (batch) / B row (gate-unit)
    const int q = lane >> 4;         // k sub-offset group / C row group
    const int blk = blockIdx.x;      // owns hidden units [4*blk, 4*blk+4)

    // ---- stage the weight slice into LDS, MFMA fragment order ----
    {
        const int p = tid >> 4;
        const int g = p & 3, v = p >> 2;
        const u16* wrow = Wall + (size_t)(g * H_ + blk * 4 + v) * C_;
        const int kb = tid & 15;
#pragma unroll
        for (int i = 0; i < 12; i++) {
            int k8 = kb + (i << 4);                      // 0..191
            bf16x8 wv = *(const bf16x8*)(wrow + (k8 << 3));
            int off16 = ((k8 >> 2) << 6) + ((k8 & 3) << 4) + p;
            *(bf16x8*)(&wlds[(size_t)off16 << 3]) = wv;
        }
    }

    // epilogue ownership: lane -> (batch b2, unit j2); c lives in a register
    const int m2 = lane & 15;
    const int v2 = lane >> 4;
    const int b2 = w * 16 + m2;
    const int j2 = blk * 4 + v2;
    const float bF = bfv[j2], bI = biv[j2], bO = bov[j2], bG = bgv[j2];
    float c_reg = 0.f;

    __syncthreads();   // wlds ready (cross-wave)

    for (int t = 0; t < S_; t++) {
        const u16* xr = xbf + ((size_t)t * B_ + w * 16 + la) * I_ + (q << 3);
        f32x4 a0 = (f32x4){0.f,0.f,0.f,0.f};
        f32x4 a1 = (f32x4){0.f,0.f,0.f,0.f};
        f32x4 a2 = (f32x4){0.f,0.f,0.f,0.f};
        f32x4 a3 = (f32x4){0.f,0.f,0.f,0.f};

        // x-part (chunks 0..15): independent of h -> runs before the sync,
        // overlapping the previous step's release chain. L2-resident.
#pragma unroll
        for (int ch = 0; ch < 16; ch += 4) {
            bf16x8 x0 = *(const bf16x8*)(xr + (ch << 5));
            bf16x8 x1 = *(const bf16x8*)(xr + ((ch + 1) << 5));
            bf16x8 x2 = *(const bf16x8*)(xr + ((ch + 2) << 5));
            bf16x8 x3 = *(const bf16x8*)(xr + ((ch + 3) << 5));
            bf16x8 w0 = *(const bf16x8*)(&wlds[(size_t)((ch    ) * 64 + lane) << 3]);
            bf16x8 w1 = *(const bf16x8*)(&wlds[(size_t)((ch + 1) * 64 + lane) << 3]);
            bf16x8 w2 = *(const bf16x8*)(&wlds[(size_t)((ch + 2) * 64 + lane) << 3]);
            bf16x8 w3 = *(const bf16x8*)(&wlds[(size_t)((ch + 3) * 64 + lane) << 3]);
            a0 = __builtin_amdgcn_mfma_f32_16x16x32_bf16(x0, w0, a0, 0, 0, 0);
            a1 = __builtin_amdgcn_mfma_f32_16x16x32_bf16(x1, w1, a1, 0, 0, 0);
            a2 = __builtin_amdgcn_mfma_f32_16x16x32_bf16(x2, w2, a2, 0, 0, 0);
            a3 = __builtin_amdgcn_mfma_f32_16x16x32_bf16(x3, w3, a3, 0, 0, 0);
        }

        // wait for h(t): PER-WAVE spin (lane 0 polls with bypassing loads).
        // No block barrier here -- each wave proceeds as soon as all 256
        // blocks flagged step t-1. Bounded spin: watchdog, not a hang.
        if (t > 0) {
            if (lane == 0) {
                const u64* cl = (const u64*)(cnt + ((t - 1) << 3));
                int guard = 0;
                for (;;) {
                    u64 s0 = __hip_atomic_load((u64*)(cl + 0), __ATOMIC_RELAXED, __HIP_MEMORY_SCOPE_AGENT);
                    u64 s1 = __hip_atomic_load((u64*)(cl + 1), __ATOMIC_RELAXED, __HIP_MEMORY_SCOPE_AGENT);
                    u64 s2 = __hip_atomic_load((u64*)(cl + 2), __ATOMIC_RELAXED, __HIP_MEMORY_SCOPE_AGENT);
                    u64 s3 = __hip_atomic_load((u64*)(cl + 3), __ATOMIC_RELAXED, __HIP_MEMORY_SCOPE_AGENT);
                    u64 s = s0 + s1 + s2 + s3;
                    s = (s & 0xffffffffull) + (s >> 32);
                    if (s == 256) break;
                    if (++guard > (1 << 14)) break;   // watchdog
                    __builtin_amdgcn_s_sleep(1);
                }
            }
            __builtin_amdgcn_sched_barrier(0);
            asm volatile("" ::: "memory");   // keep h loads below the spin
        }

        // h-part (chunks 16..47): issue ALL 32 loads first (hb[] fully
        // unrolled -> static indices -> registers), then consume. One MALL
        // round trip of latency instead of eight (r5 was VGPR-starved at 68).
        const u16* hr = hhi + ((size_t)t * B_ + w * 16 + la) * H_ + (q << 3);
        bf16x8 hb[32];
#pragma unroll
        for (int ch = 0; ch < 32; ch++)
            hb[ch] = *(const bf16x8*)(hr + (ch << 5));
#pragma unroll
        for (int ch = 0; ch < 32; ch += 4) {
            bf16x8 w0 = *(const bf16x8*)(&wlds[(size_t)((16 + ch) * 64 + lane) << 3]);
            bf16x8 w1 = *(const bf16x8*)(&wlds[(size_t)((17 + ch) * 64 + lane) << 3]);
            bf16x8 w2 = *(const bf16x8*)(&wlds[(size_t)((18 + ch) * 64 + lane) << 3]);
            bf16x8 w3 = *(const bf16x8*)(&wlds[(size_t)((19 + ch) * 64 + lane) << 3]);
            a0 = __builtin_amdgcn_mfma_f32_16x16x32_bf16(hb[ch    ], w0, a0, 0, 0, 0);
            a1 = __builtin_amdgcn_mfma_f32_16x16x32_bf16(hb[ch + 1], w1, a1, 0, 0, 0);
            a2 = __builtin_amdgcn_mfma_f32_16x16x32_bf16(hb[ch + 2], w2, a2, 0, 0, 0);
            a3 = __builtin_amdgcn_mfma_f32_16x16x32_bf16(hb[ch + 3], w3, a3, 0, 0, 0);
        }
        f32x4 acc = (a0 + a1) + (a2 + a3);

        // per-wave transpose: C[batch q*4+r][gate-unit la] -> 4 gates per lane
        // (ex is wave-private: no cross-wave barrier needed)
#pragma unroll
        for (int r = 0; r < 4; r++) ex[w][q * 4 + r][la] = acc[r];
        float s0 = ex[w][m2][(v2 << 2) + 0];
        float s1 = ex[w][m2][(v2 << 2) + 1];
        float s2 = ex[w][m2][(v2 << 2) + 2];
        float s3 = ex[w][m2][(v2 << 2) + 3];

        float fg = sigm(s0 + bF);
        float ig = sigm(s1 + bI);
        float og = sigm(s2 + bO);
        float gg = tanhf(s3 + bG);
        c_reg = fg * c_reg + ig * gg;
        float hn = og * tanhf(c_reg);
        u16 hb2 = f2bf(hn);
        hxh[b2][v2] = hb2;
        hxl[b2][v2] = f2bf(hn - bf2f(hb2));

        __syncthreads();   // h staging complete (cross-wave: wave0 reads all)

        // coalesced h writeout: wave 0, one 8B store per batch row.
        // hi: write-through agent atomics (MALL-visible before the flag);
        // lo: plain (only k_pred reads it, after a kernel boundary).
        if (tid < 64) {
            u64 hv = *(const u64*)&hxh[tid][0];
            u64 lv = *(const u64*)&hxl[tid][0];
            size_t ro = ((size_t)(t + 1) * B_ + tid) * H_ + (size_t)blk * 4;
            __hip_atomic_store((u64*)(hhi + ro), hv, __ATOMIC_RELAXED, __HIP_MEMORY_SCOPE_AGENT);
            *(u64*)(hlo + ro) = lv;
        }
        if (tid == 0) {
            // all step-t h stores were issued by THIS wave -> vmcnt covers them
            asm volatile("s_waitcnt vmcnt(0)" ::: "memory");
            __hip_atomic_fetch_add(&cnt[(t << 3) + (blk & 7)], 1,
                                   __ATOMIC_RELAXED, __HIP_MEMORY_SCOPE_AGENT);
        }
        // hxh/hxl reuse is safe: any wave's step-t+1 epilogue writes require
        // passing spin(t), which requires this block's flag(t), which is only
        // raised after hxh/hxl[t] were consumed by wave 0.
    }
}

// ---- final projection: out = H_all @ Wy^T + by (bf16 hi/lo, ~fp32 quality)
__global__ __launch_bounds__(256) void k_pred(
    const u16* __restrict__ ah, const u16* __restrict__ al,
    const u16* __restrict__ wyh, const u16* __restrict__ wyl,
    const float* __restrict__ by, float* __restrict__ out)
{
    const int tid = threadIdx.x;
    const int wv = tid >> 6;
    const int lane = tid & 63;
    const int la = lane & 15;
    const int kg = (lane >> 4) * 8;
    const int m0 = blockIdx.x * 64;
    const int n0 = blockIdx.y * 64 + wv * 16;

    const u16* bh = wyh + (size_t)(n0 + la) * H_ + kg;
    const u16* bl = wyl + (size_t)(n0 + la) * H_ + kg;

    f32x4 acc[4];
#pragma unroll
    for (int m = 0; m < 4; m++) acc[m] = (f32x4){0.f, 0.f, 0.f, 0.f};

    for (int k = 0; k < H_; k += 32) {
        bf16x8 bhh = *(const bf16x8*)(bh + k);
        bf16x8 bll = *(const bf16x8*)(bl + k);
#pragma unroll
        for (int m = 0; m < 4; m++) {
            size_t arow = (size_t)(m0 + m * 16 + la);
            bf16x8 aa  = *(const bf16x8*)(ah + arow * H_ + k + kg);
            bf16x8 aal = *(const bf16x8*)(al + arow * H_ + k + kg);
            acc[m] = __builtin_amdgcn_mfma_f32_16x16x32_bf16(aal, bhh, acc[m], 0, 0, 0);
            acc[m] = __builtin_amdgcn_mfma_f32_16x16x32_bf16(aa, bll, acc[m], 0, 0, 0);
            acc[m] = __builtin_amdgcn_mfma_f32_16x16x32_bf16(aa, bhh, acc[m], 0, 0, 0);
        }
    }

#pragma unroll
    for (int m = 0; m < 4; m++)
#pragma unroll
        for (int r = 0; r < 4; r++) {
            int row = m0 + m * 16 + (lane >> 4) * 4 + r;
            int col = n0 + la;
            out[(size_t)row * O_ + col] = acc[m][r] + by[col];
        }
}

// ---- host ------------------------------------------------------------------

extern "C" void kernel_launch(void* const* d_in, const int* in_sizes, int n_in,
                              void* d_out, int out_size, void* d_ws, size_t ws_size,
                              hipStream_t stream) {
    const float* x   = (const float*)d_in[0];
    const float* Wf  = (const float*)d_in[1];
    const float* bfv = (const float*)d_in[2];
    const float* Wi  = (const float*)d_in[3];
    const float* biv = (const float*)d_in[4];
    const float* Wo  = (const float*)d_in[5];
    const float* bov = (const float*)d_in[6];
    const float* Wg  = (const float*)d_in[7];
    const float* bgv = (const float*)d_in[8];
    const float* Wy  = (const float*)d_in[9];
    const float* by  = (const float*)d_in[10];
    float* out = (float*)d_out;

    char* ws = (char*)d_ws;
    size_t off = 0;
    auto alloc = [&](size_t bytes) {
        char* p = ws + off;
        off += (bytes + 255) & ~(size_t)255;
        return p;
    };
    u16*   Wall = (u16*)alloc((size_t)NG_ * C_ * 2);
    u16*   Wyhi = (u16*)alloc((size_t)O_ * H_ * 2);
    u16*   Wylo = (u16*)alloc((size_t)O_ * H_ * 2);
    u16*   xbf  = (u16*)alloc((size_t)S_ * B_ * I_ * 2);
    u16*   hhi  = (u16*)alloc((size_t)(S_ + 1) * B_ * H_ * 2);
    u16*   hlo  = (u16*)alloc((size_t)(S_ + 1) * B_ * H_ * 2);
    int*   cnt  = (int*)alloc((size_t)S_ * 8 * 4);

    (void)hipMemsetAsync(hhi, 0, (size_t)B_ * H_ * 2, stream);   // h(0) = 0
    (void)hipMemsetAsync(cnt, 0, (size_t)S_ * 8 * 4, stream);    // step counters

    k_pack_w <<<3072, 256, 0, stream>>>(Wf, Wi, Wo, Wg, Wall);
    k_pack_wy<<<256,  256, 0, stream>>>(Wy, Wyhi, Wylo);
    k_pack_x <<<8192, 256, 0, stream>>>(x, xbf);

    k_lstm<<<256, 256, 0, stream>>>(Wall, xbf, bfv, biv, bov, bgv, hhi, hlo, cnt);

    k_pred<<<dim3(512, 8), 256, 0, stream>>>(hhi + (size_t)B_ * H_, hlo + (size_t)B_ * H_,
                                             Wyhi, Wylo, by, out);
}

// Round 9
// 4842.162 us; speedup vs baseline: 2.2318x; 1.0016x over previous
//
#include <hip/hip_runtime.h>

#define S_ 512
#define B_ 64
#define I_ 512
#define H_ 1024
#define O_ 512
#define C_ 1536   // I_ + H_
#define NG_ 4096  // 4*H_

typedef unsigned short u16;
typedef unsigned long long u64;
typedef __attribute__((ext_vector_type(8))) short bf16x8;
typedef __attribute__((ext_vector_type(8))) unsigned short u16x8;
typedef __attribute__((ext_vector_type(4))) float f32x4;

__device__ __forceinline__ u16 f2bf(float f) {
    union { float f; unsigned int u; } v; v.f = f;
    unsigned int u = v.u;
    unsigned int r = (u + 0x7fffu + ((u >> 16) & 1u)) >> 16;
    return (u16)r;
}
__device__ __forceinline__ float bf2f(u16 h) {
    union { unsigned int u; float f; } v; v.u = ((unsigned int)h) << 16;
    return v.f;
}
__device__ __forceinline__ float sigm(float x) { return 1.0f / (1.0f + __expf(-x)); }

// ---- packing kernels -------------------------------------------------------

__global__ void k_pack_w(const float* __restrict__ Wf, const float* __restrict__ Wi,
                         const float* __restrict__ Wo, const float* __restrict__ Wg,
                         u16* __restrict__ Wall) {
    size_t i8 = ((size_t)blockIdx.x * blockDim.x + threadIdx.x) * 8;
    if (i8 >= (size_t)NG_ * C_) return;
    size_t n = i8 / C_;
    size_t k = i8 - n * C_;
    const float* Ws[4] = {Wf, Wi, Wo, Wg};
    const float* src = Ws[n >> 10] + (n & 1023) * C_ + k;
    u16x8 o;
#pragma unroll
    for (int j = 0; j < 8; j++) o[j] = f2bf(src[j]);
    *(u16x8*)(Wall + i8) = o;
}

__global__ void k_pack_wy(const float* __restrict__ Wy,
                          u16* __restrict__ hi, u16* __restrict__ lo) {
    size_t i8 = ((size_t)blockIdx.x * blockDim.x + threadIdx.x) * 8;
    if (i8 >= (size_t)O_ * H_) return;
    u16x8 oh, ol;
#pragma unroll
    for (int j = 0; j < 8; j++) {
        float v = Wy[i8 + j];
        oh[j] = f2bf(v);
        ol[j] = f2bf(v - bf2f(oh[j]));
    }
    *(u16x8*)(hi + i8) = oh;
    *(u16x8*)(lo + i8) = ol;
}

__global__ void k_pack_x(const float* __restrict__ x, u16* __restrict__ xb) {
    size_t i8 = ((size_t)blockIdx.x * blockDim.x + threadIdx.x) * 8;
    if (i8 >= (size_t)S_ * B_ * I_) return;
    u16x8 o;
#pragma unroll
    for (int j = 0; j < 8; j++) o[j] = f2bf(x[i8 + j]);
    *(u16x8*)(xb + i8) = o;
}

// ---- persistent LSTM: all 512 steps in one kernel --------------------------
// 256 blocks x 256 threads, 1 block/CU (grid==CU count -> always co-resident).
// Block owns 4 hidden units x 4 gates x full K; 48 KB weights in LDS for the
// whole sequence. Wave w owns batch rows [16w,16w+16): 48 MFMAs/step,
// c-state in a register.
// Round-6 post-mortem: VGPR_Count stayed 68 -> compiler re-sank the hb[32]
// prefetch into the MFMA loop (4 loads in flight -> ~8 serial MALL round
// trips ~3us/step). This round pins the schedule: all 32 h-loads ISSUE
// before the first h-MFMA via sched_barrier(0) (no instruction may cross).
// Verification hook: VGPR_Count must jump to ~200; if still ~68 the
// compiler defeated it again (next: inline-asm loads).
// Coherence protocol unchanged (proven r5/r6): h-hi written with sc-bit
// write-through atomics, read with plain cached loads (fresh lines only);
// release = wave0 vmcnt(0) then relaxed fetch_add; acquire = lane0 bypass
// polls. Zero cache-maintenance instructions. Spin is BOUNDED (watchdog).
__global__ __launch_bounds__(256, 1) void k_lstm(
    const u16* __restrict__ Wall,   // [4096][1536] bf16
    const u16* __restrict__ xbf,    // [S][64][512] bf16
    const float* __restrict__ bfv, const float* __restrict__ biv,
    const float* __restrict__ bov, const float* __restrict__ bgv,
    u16* __restrict__ hhi,          // [S+1][64][1024] bf16
    u16* __restrict__ hlo,          // [S+1][64][1024] bf16 residual
    int* __restrict__ cnt)          // [S][8] step-completion counters
{
    __shared__ __align__(16) u16 wlds[48 * 64 * 8];  // 48 KB: [chunk][lane][8]
    __shared__ float ex[4][16][17];                  // per-wave gate exchange
    __shared__ __align__(8) u16 hxh[64][4];          // h-hi staging [batch][unit]
    __shared__ __align__(8) u16 hxl[64][4];          // h-lo staging

    const int tid = threadIdx.x;
    const int w = tid >> 6;          // wave -> batch rows [16w,16w+16)
    const int lane = tid & 63;
    const int la = lane & 15;        // A row (batch) / B row (gate-unit)
    const int q = lane >> 4;         // k sub-offset group / C row group
    const int blk = blockIdx.x;      // owns hidden units [4*blk, 4*blk+4)

    // ---- stage the weight slice into LDS, MFMA fragment order ----
    {
        const int p = tid >> 4;
        const int g = p & 3, v = p >> 2;
        const u16* wrow = Wall + (size_t)(g * H_ + blk * 4 + v) * C_;
        const int kb = tid & 15;
#pragma unroll
        for (int i = 0; i < 12; i++) {
            int k8 = kb + (i << 4);                      // 0..191
            bf16x8 wv = *(const bf16x8*)(wrow + (k8 << 3));
            int off16 = ((k8 >> 2) << 6) + ((k8 & 3) << 4) + p;
            *(bf16x8*)(&wlds[(size_t)off16 << 3]) = wv;
        }
    }

    // epilogue ownership: lane -> (batch b2, unit j2); c lives in a register
    const int m2 = lane & 15;
    const int v2 = lane >> 4;
    const int b2 = w * 16 + m2;
    const int j2 = blk * 4 + v2;
    const float bF = bfv[j2], bI = biv[j2], bO = bov[j2], bG = bgv[j2];
    float c_reg = 0.f;

    __syncthreads();   // wlds ready (cross-wave)

    for (int t = 0; t < S_; t++) {
        const u16* xr = xbf + ((size_t)t * B_ + w * 16 + la) * I_ + (q << 3);
        f32x4 a0 = (f32x4){0.f,0.f,0.f,0.f};
        f32x4 a1 = (f32x4){0.f,0.f,0.f,0.f};
        f32x4 a2 = (f32x4){0.f,0.f,0.f,0.f};
        f32x4 a3 = (f32x4){0.f,0.f,0.f,0.f};

        // x-part (chunks 0..15): independent of h -> runs before the sync,
        // overlapping the previous step's release chain. L2-resident.
#pragma unroll
        for (int ch = 0; ch < 16; ch += 4) {
            bf16x8 x0 = *(const bf16x8*)(xr + (ch << 5));
            bf16x8 x1 = *(const bf16x8*)(xr + ((ch + 1) << 5));
            bf16x8 x2 = *(const bf16x8*)(xr + ((ch + 2) << 5));
            bf16x8 x3 = *(const bf16x8*)(xr + ((ch + 3) << 5));
            bf16x8 w0 = *(const bf16x8*)(&wlds[(size_t)((ch    ) * 64 + lane) << 3]);
            bf16x8 w1 = *(const bf16x8*)(&wlds[(size_t)((ch + 1) * 64 + lane) << 3]);
            bf16x8 w2 = *(const bf16x8*)(&wlds[(size_t)((ch + 2) * 64 + lane) << 3]);
            bf16x8 w3 = *(const bf16x8*)(&wlds[(size_t)((ch + 3) * 64 + lane) << 3]);
            a0 = __builtin_amdgcn_mfma_f32_16x16x32_bf16(x0, w0, a0, 0, 0, 0);
            a1 = __builtin_amdgcn_mfma_f32_16x16x32_bf16(x1, w1, a1, 0, 0, 0);
            a2 = __builtin_amdgcn_mfma_f32_16x16x32_bf16(x2, w2, a2, 0, 0, 0);
            a3 = __builtin_amdgcn_mfma_f32_16x16x32_bf16(x3, w3, a3, 0, 0, 0);
        }

        // wait for h(t): PER-WAVE spin (lane 0 polls with bypassing loads).
        // Bounded spin: watchdog, not a hang.
        if (t > 0) {
            if (lane == 0) {
                const u64* cl = (const u64*)(cnt + ((t - 1) << 3));
                int guard = 0;
                for (;;) {
                    u64 s0 = __hip_atomic_load((u64*)(cl + 0), __ATOMIC_RELAXED, __HIP_MEMORY_SCOPE_AGENT);
                    u64 s1 = __hip_atomic_load((u64*)(cl + 1), __ATOMIC_RELAXED, __HIP_MEMORY_SCOPE_AGENT);
                    u64 s2 = __hip_atomic_load((u64*)(cl + 2), __ATOMIC_RELAXED, __HIP_MEMORY_SCOPE_AGENT);
                    u64 s3 = __hip_atomic_load((u64*)(cl + 3), __ATOMIC_RELAXED, __HIP_MEMORY_SCOPE_AGENT);
                    u64 s = s0 + s1 + s2 + s3;
                    s = (s & 0xffffffffull) + (s >> 32);
                    if (s == 256) break;
                    if (++guard > (1 << 14)) break;   // watchdog
                    __builtin_amdgcn_s_sleep(1);
                }
            }
            __builtin_amdgcn_sched_barrier(0);
            asm volatile("" ::: "memory");   // keep h loads below the spin
        }

        // h-part (chunks 16..47): ISSUE all 32 loads, then a hard schedule
        // fence, then consume. sched_barrier(0) forbids the scheduler from
        // sinking loads past it (r6: without this, compiler kept only ~4 in
        // flight at VGPR=68 -> ~8 serial MALL round trips).
        const u16* hr = hhi + ((size_t)t * B_ + w * 16 + la) * H_ + (q << 3);
        bf16x8 hb[32];
#pragma unroll
        for (int ch = 0; ch < 32; ch++)
            hb[ch] = *(const bf16x8*)(hr + (ch << 5));
        __builtin_amdgcn_sched_barrier(0);   // all 32 loads issued above here
#pragma unroll
        for (int ch = 0; ch < 32; ch += 4) {
            bf16x8 w0 = *(const bf16x8*)(&wlds[(size_t)((16 + ch) * 64 + lane) << 3]);
            bf16x8 w1 = *(const bf16x8*)(&wlds[(size_t)((17 + ch) * 64 + lane) << 3]);
            bf16x8 w2 = *(const bf16x8*)(&wlds[(size_t)((18 + ch) * 64 + lane) << 3]);
            bf16x8 w3 = *(const bf16x8*)(&wlds[(size_t)((19 + ch) * 64 + lane) << 3]);
            a0 = __builtin_amdgcn_mfma_f32_16x16x32_bf16(hb[ch    ], w0, a0, 0, 0, 0);
            a1 = __builtin_amdgcn_mfma_f32_16x16x32_bf16(hb[ch + 1], w1, a1, 0, 0, 0);
            a2 = __builtin_amdgcn_mfma_f32_16x16x32_bf16(hb[ch + 2], w2, a2, 0, 0, 0);
            a3 = __builtin_amdgcn_mfma_f32_16x16x32_bf16(hb[ch + 3], w3, a3, 0, 0, 0);
        }
        f32x4 acc = (a0 + a1) + (a2 + a3);

        // per-wave transpose: C[batch q*4+r][gate-unit la] -> 4 gates per lane
        // (ex is wave-private: no cross-wave barrier needed)
#pragma unroll
        for (int r = 0; r < 4; r++) ex[w][q * 4 + r][la] = acc[r];
        float s0 = ex[w][m2][(v2 << 2) + 0];
        float s1 = ex[w][m2][(v2 << 2) + 1];
        float s2 = ex[w][m2][(v2 << 2) + 2];
        float s3 = ex[w][m2][(v2 << 2) + 3];

        float fg = sigm(s0 + bF);
        float ig = sigm(s1 + bI);
        float og = sigm(s2 + bO);
        float gg = tanhf(s3 + bG);
        c_reg = fg * c_reg + ig * gg;
        float hn = og * tanhf(c_reg);
        u16 hb2 = f2bf(hn);
        hxh[b2][v2] = hb2;
        hxl[b2][v2] = f2bf(hn - bf2f(hb2));

        __syncthreads();   // h staging complete (cross-wave: wave0 reads all)

        // coalesced h writeout: wave 0, one 8B store per batch row.
        // hi: write-through agent atomics (MALL-visible before the flag);
        // lo: plain (only k_pred reads it, after a kernel boundary).
        if (tid < 64) {
            u64 hv = *(const u64*)&hxh[tid][0];
            u64 lv = *(const u64*)&hxl[tid][0];
            size_t ro = ((size_t)(t + 1) * B_ + tid) * H_ + (size_t)blk * 4;
            __hip_atomic_store((u64*)(hhi + ro), hv, __ATOMIC_RELAXED, __HIP_MEMORY_SCOPE_AGENT);
            *(u64*)(hlo + ro) = lv;
        }
        if (tid == 0) {
            // all step-t h stores were issued by THIS wave -> vmcnt covers them
            asm volatile("s_waitcnt vmcnt(0)" ::: "memory");
            __hip_atomic_fetch_add(&cnt[(t << 3) + (blk & 7)], 1,
                                   __ATOMIC_RELAXED, __HIP_MEMORY_SCOPE_AGENT);
        }
        // hxh/hxl reuse is safe: any wave's step-t+1 epilogue writes require
        // passing spin(t), which requires this block's flag(t), which is only
        // raised after hxh/hxl[t] were consumed by wave 0.
    }
}

// ---- final projection: out = H_all @ Wy^T + by (bf16 hi/lo, ~fp32 quality)
__global__ __launch_bounds__(256) void k_pred(
    const u16* __restrict__ ah, const u16* __restrict__ al,
    const u16* __restrict__ wyh, const u16* __restrict__ wyl,
    const float* __restrict__ by, float* __restrict__ out)
{
    const int tid = threadIdx.x;
    const int wv = tid >> 6;
    const int lane = tid & 63;
    const int la = lane & 15;
    const int kg = (lane >> 4) * 8;
    const int m0 = blockIdx.x * 64;
    const int n0 = blockIdx.y * 64 + wv * 16;

    const u16* bh = wyh + (size_t)(n0 + la) * H_ + kg;
    const u16* bl = wyl + (size_t)(n0 + la) * H_ + kg;

    f32x4 acc[4];
#pragma unroll
    for (int m = 0; m < 4; m++) acc[m] = (f32x4){0.f, 0.f, 0.f, 0.f};

    for (int k = 0; k < H_; k += 32) {
        bf16x8 bhh = *(const bf16x8*)(bh + k);
        bf16x8 bll = *(const bf16x8*)(bl + k);
#pragma unroll
        for (int m = 0; m < 4; m++) {
            size_t arow = (size_t)(m0 + m * 16 + la);
            bf16x8 aa  = *(const bf16x8*)(ah + arow * H_ + k + kg);
            bf16x8 aal = *(const bf16x8*)(al + arow * H_ + k + kg);
            acc[m] = __builtin_amdgcn_mfma_f32_16x16x32_bf16(aal, bhh, acc[m], 0, 0, 0);
            acc[m] = __builtin_amdgcn_mfma_f32_16x16x32_bf16(aa, bll, acc[m], 0, 0, 0);
            acc[m] = __builtin_amdgcn_mfma_f32_16x16x32_bf16(aa, bhh, acc[m], 0, 0, 0);
        }
    }

#pragma unroll
    for (int m = 0; m < 4; m++)
#pragma unroll
        for (int r = 0; r < 4; r++) {
            int row = m0 + m * 16 + (lane >> 4) * 4 + r;
            int col = n0 + la;
            out[(size_t)row * O_ + col] = acc[m][r] + by[col];
        }
}

// ---- host ------------------------------------------------------------------

extern "C" void kernel_launch(void* const* d_in, const int* in_sizes, int n_in,
                              void* d_out, int out_size, void* d_ws, size_t ws_size,
                              hipStream_t stream) {
    const float* x   = (const float*)d_in[0];
    const float* Wf  = (const float*)d_in[1];
    const float* bfv = (const float*)d_in[2];
    const float* Wi  = (const float*)d_in[3];
    const float* biv = (const float*)d_in[4];
    const float* Wo  = (const float*)d_in[5];
    const float* bov = (const float*)d_in[6];
    const float* Wg  = (const float*)d_in[7];
    const float* bgv = (const float*)d_in[8];
    const float* Wy  = (const float*)d_in[9];
    const float* by  = (const float*)d_in[10];
    float* out = (float*)d_out;

    char* ws = (char*)d_ws;
    size_t off = 0;
    auto alloc = [&](size_t bytes) {
        char* p = ws + off;
        off += (bytes + 255) & ~(size_t)255;
        return p;
    };
    u16*   Wall = (u16*)alloc((size_t)NG_ * C_ * 2);
    u16*   Wyhi = (u16*)alloc((size_t)O_ * H_ * 2);
    u16*   Wylo = (u16*)alloc((size_t)O_ * H_ * 2);
    u16*   xbf  = (u16*)alloc((size_t)S_ * B_ * I_ * 2);
    u16*   hhi  = (u16*)alloc((size_t)(S_ + 1) * B_ * H_ * 2);
    u16*   hlo  = (u16*)alloc((size_t)(S_ + 1) * B_ * H_ * 2);
    int*   cnt  = (int*)alloc((size_t)S_ * 8 * 4);

    (void)hipMemsetAsync(hhi, 0, (size_t)B_ * H_ * 2, stream);   // h(0) = 0
    (void)hipMemsetAsync(cnt, 0, (size_t)S_ * 8 * 4, stream);    // step counters

    k_pack_w <<<3072, 256, 0, stream>>>(Wf, Wi, Wo, Wg, Wall);
    k_pack_wy<<<256,  256, 0, stream>>>(Wy, Wyhi, Wylo);
    k_pack_x <<<8192, 256, 0, stream>>>(x, xbf);

    k_lstm<<<256, 256, 0, stream>>>(Wall, xbf, bfv, biv, bov, bgv, hhi, hlo, cnt);

    k_pred<<<dim3(512, 8), 256, 0, stream>>>(hhi + (size_t)B_ * H_, hlo + (size_t)B_ * H_,
                                             Wyhi, Wylo, by, out);
}

// Round 11
// 4378.046 us; speedup vs baseline: 2.4684x; 1.1060x over previous
//
#include <hip/hip_runtime.h>

#define S_ 512
#define B_ 64
#define I_ 512
#define H_ 1024
#define O_ 512
#define C_ 1536   // I_ + H_
#define NG_ 4096  // 4*H_

typedef unsigned short u16;
typedef unsigned long long u64;
typedef __attribute__((ext_vector_type(8))) short bf16x8;
typedef __attribute__((ext_vector_type(8))) unsigned short u16x8;
typedef __attribute__((ext_vector_type(4))) float f32x4;

__device__ __forceinline__ u16 f2bf(float f) {
    union { float f; unsigned int u; } v; v.f = f;
    unsigned int u = v.u;
    unsigned int r = (u + 0x7fffu + ((u >> 16) & 1u)) >> 16;
    return (u16)r;
}
__device__ __forceinline__ float bf2f(u16 h) {
    union { unsigned int u; float f; } v; v.u = ((unsigned int)h) << 16;
    return v.f;
}
__device__ __forceinline__ float sigm(float x) { return 1.0f / (1.0f + __expf(-x)); }

// ---- packing kernels -------------------------------------------------------

__global__ void k_pack_w(const float* __restrict__ Wf, const float* __restrict__ Wi,
                         const float* __restrict__ Wo, const float* __restrict__ Wg,
                         u16* __restrict__ Wall) {
    size_t i8 = ((size_t)blockIdx.x * blockDim.x + threadIdx.x) * 8;
    if (i8 >= (size_t)NG_ * C_) return;
    size_t n = i8 / C_;
    size_t k = i8 - n * C_;
    const float* Ws[4] = {Wf, Wi, Wo, Wg};
    const float* src = Ws[n >> 10] + (n & 1023) * C_ + k;
    u16x8 o;
#pragma unroll
    for (int j = 0; j < 8; j++) o[j] = f2bf(src[j]);
    *(u16x8*)(Wall + i8) = o;
}

__global__ void k_pack_wy(const float* __restrict__ Wy,
                          u16* __restrict__ hi, u16* __restrict__ lo) {
    size_t i8 = ((size_t)blockIdx.x * blockDim.x + threadIdx.x) * 8;
    if (i8 >= (size_t)O_ * H_) return;
    u16x8 oh, ol;
#pragma unroll
    for (int j = 0; j < 8; j++) {
        float v = Wy[i8 + j];
        oh[j] = f2bf(v);
        ol[j] = f2bf(v - bf2f(oh[j]));
    }
    *(u16x8*)(hi + i8) = oh;
    *(u16x8*)(lo + i8) = ol;
}

__global__ void k_pack_x(const float* __restrict__ x, u16* __restrict__ xb) {
    size_t i8 = ((size_t)blockIdx.x * blockDim.x + threadIdx.x) * 8;
    if (i8 >= (size_t)S_ * B_ * I_) return;
    u16x8 o;
#pragma unroll
    for (int j = 0; j < 8; j++) o[j] = f2bf(x[i8 + j]);
    *(u16x8*)(xb + i8) = o;
}

// ---- persistent LSTM: all 512 steps in one kernel --------------------------
// 256 blocks x 256 threads, 1 block/CU. Block owns 4 units x 4 gates x full K;
// 48 KB weights in LDS. Wave w owns batch rows [16w,16w+16). c in a register.
// Round-9 post-mortem: h-prefetch fixes were no-ops AND per-wave polling was
// neutral -> dominant term is TCC channel contention on the counter LINE:
// all 8 counters of a step lived in ONE 64B line; 256 fetch_adds + ~1024
// pollers x 4 u64 bypass loads serialized on one MALL channel (~4 req/cy
// offered vs ~1/cy service) -> release queued behind poll flood, ~4-6us/step.
// Fix A: counters SPREAD 2KB apart (cnt[g*S+t], 8 channels); tid0-only poll
// (256 pollers), 8 spread u32 loads + s_sleep(4) backoff, then barrier.
// Fix B: h-loads via 32 VOLATILE inline-asm global_load_dwordx4 (compiler
// cannot re-sink volatile asm; r6/r9 showed it re-sinks C++ loads), then
// s_waitcnt vmcnt(0) + sched_barrier(0) (rule #18), then MFMAs.
// Counter signatures: VGPR ~200+ proves B; sync fix shows in dur_us.
// Coherence unchanged (proven r5-r9): h-hi sc-bit write-through stores, plain
// cached reads of fresh lines, wave0 vmcnt(0)+relaxed fetch_add release.
// Zero cache-maintenance instructions. Spin BOUNDED (watchdog).
__global__ __launch_bounds__(256, 1) void k_lstm(
    const u16* __restrict__ Wall,   // [4096][1536] bf16
    const u16* __restrict__ xbf,    // [S][64][512] bf16
    const float* __restrict__ bfv, const float* __restrict__ biv,
    const float* __restrict__ bov, const float* __restrict__ bgv,
    u16* __restrict__ hhi,          // [S+1][64][1024] bf16
    u16* __restrict__ hlo,          // [S+1][64][1024] bf16 residual
    int* __restrict__ cnt)          // [8][S] spread step counters
{
    __shared__ __align__(16) u16 wlds[48 * 64 * 8];  // 48 KB: [chunk][lane][8]
    __shared__ float ex[4][16][17];                  // per-wave gate exchange
    __shared__ __align__(8) u16 hxh[64][4];          // h-hi staging [batch][unit]
    __shared__ __align__(8) u16 hxl[64][4];          // h-lo staging

    const int tid = threadIdx.x;
    const int w = tid >> 6;          // wave -> batch rows [16w,16w+16)
    const int lane = tid & 63;
    const int la = lane & 15;        // A row (batch) / B row (gate-unit)
    const int q = lane >> 4;         // k sub-offset group / C row group
    const int blk = blockIdx.x;      // owns hidden units [4*blk, 4*blk+4)

    // ---- stage the weight slice into LDS, MFMA fragment order ----
    {
        const int p = tid >> 4;
        const int g = p & 3, v = p >> 2;
        const u16* wrow = Wall + (size_t)(g * H_ + blk * 4 + v) * C_;
        const int kb = tid & 15;
#pragma unroll
        for (int i = 0; i < 12; i++) {
            int k8 = kb + (i << 4);                      // 0..191
            bf16x8 wv = *(const bf16x8*)(wrow + (k8 << 3));
            int off16 = ((k8 >> 2) << 6) + ((k8 & 3) << 4) + p;
            *(bf16x8*)(&wlds[(size_t)off16 << 3]) = wv;
        }
    }

    // epilogue ownership: lane -> (batch b2, unit j2); c lives in a register
    const int m2 = lane & 15;
    const int v2 = lane >> 4;
    const int b2 = w * 16 + m2;
    const int j2 = blk * 4 + v2;
    const float bF = bfv[j2], bI = biv[j2], bO = bov[j2], bG = bgv[j2];
    float c_reg = 0.f;

    __syncthreads();   // wlds ready (cross-wave)

    for (int t = 0; t < S_; t++) {
        const u16* xr = xbf + ((size_t)t * B_ + w * 16 + la) * I_ + (q << 3);
        f32x4 a0 = (f32x4){0.f,0.f,0.f,0.f};
        f32x4 a1 = (f32x4){0.f,0.f,0.f,0.f};
        f32x4 a2 = (f32x4){0.f,0.f,0.f,0.f};
        f32x4 a3 = (f32x4){0.f,0.f,0.f,0.f};

        // x-part (chunks 0..15): independent of h -> runs before the sync,
        // filling the detect window. L2-resident.
#pragma unroll
        for (int ch = 0; ch < 16; ch += 4) {
            bf16x8 x0 = *(const bf16x8*)(xr + (ch << 5));
            bf16x8 x1 = *(const bf16x8*)(xr + ((ch + 1) << 5));
            bf16x8 x2 = *(const bf16x8*)(xr + ((ch + 2) << 5));
            bf16x8 x3 = *(const bf16x8*)(xr + ((ch + 3) << 5));
            bf16x8 w0 = *(const bf16x8*)(&wlds[(size_t)((ch    ) * 64 + lane) << 3]);
            bf16x8 w1 = *(const bf16x8*)(&wlds[(size_t)((ch + 1) * 64 + lane) << 3]);
            bf16x8 w2 = *(const bf16x8*)(&wlds[(size_t)((ch + 2) * 64 + lane) << 3]);
            bf16x8 w3 = *(const bf16x8*)(&wlds[(size_t)((ch + 3) * 64 + lane) << 3]);
            a0 = __builtin_amdgcn_mfma_f32_16x16x32_bf16(x0, w0, a0, 0, 0, 0);
            a1 = __builtin_amdgcn_mfma_f32_16x16x32_bf16(x1, w1, a1, 0, 0, 0);
            a2 = __builtin_amdgcn_mfma_f32_16x16x32_bf16(x2, w2, a2, 0, 0, 0);
            a3 = __builtin_amdgcn_mfma_f32_16x16x32_bf16(x3, w3, a3, 0, 0, 0);
        }

        // wait for h(t): tid0 polls the 8 SPREAD counters (8 channels, one
        // u32 load each) with s_sleep backoff; then block barrier.
        if (t > 0) {
            if (tid == 0) {
                int guard = 0;
                for (;;) {
                    int s = 0;
#pragma unroll
                    for (int g = 0; g < 8; g++)
                        s += __hip_atomic_load(&cnt[g * S_ + (t - 1)],
                                               __ATOMIC_RELAXED, __HIP_MEMORY_SCOPE_AGENT);
                    if (s == 256) break;
                    if (++guard > (1 << 12)) break;   // watchdog
                    __builtin_amdgcn_s_sleep(4);
                }
            }
            __syncthreads();
            asm volatile("" ::: "memory");   // keep h loads below the spin
        }

        // h-part (chunks 16..47): 32 VOLATILE asm loads (cannot be re-sunk),
        // single drain, then consume. Offsets are ch*64 bytes (fit 13-bit imm).
        const u16* hr = hhi + ((size_t)t * B_ + w * 16 + la) * H_ + (q << 3);
        bf16x8 hb0, hb1, hb2, hb3, hb4, hb5, hb6, hb7,
               hb8, hb9, hb10, hb11, hb12, hb13, hb14, hb15,
               hb16, hb17, hb18, hb19, hb20, hb21, hb22, hb23,
               hb24, hb25, hb26, hb27, hb28, hb29, hb30, hb31;
#define HL(n, off) asm volatile("global_load_dwordx4 %0, %1, off offset:" #off \
                                : "=&v"(hb##n) : "v"(hr) : "memory")
        HL(0, 0);     HL(1, 64);    HL(2, 128);   HL(3, 192);
        HL(4, 256);   HL(5, 320);   HL(6, 384);   HL(7, 448);
        HL(8, 512);   HL(9, 576);   HL(10, 640);  HL(11, 704);
        HL(12, 768);  HL(13, 832);  HL(14, 896);  HL(15, 960);
        HL(16, 1024); HL(17, 1088); HL(18, 1152); HL(19, 1216);
        HL(20, 1280); HL(21, 1344); HL(22, 1408); HL(23, 1472);
        HL(24, 1536); HL(25, 1600); HL(26, 1664); HL(27, 1728);
        HL(28, 1792); HL(29, 1856); HL(30, 1920); HL(31, 1984);
#undef HL
        asm volatile("s_waitcnt vmcnt(0)" ::: "memory");
        __builtin_amdgcn_sched_barrier(0);   // rule #18: pin MFMAs below wait

#define HSTEP(c, hA, hB, hC, hD) { \
        bf16x8 w0_ = *(const bf16x8*)(&wlds[(size_t)((16 + (c)) * 64 + lane) << 3]); \
        bf16x8 w1_ = *(const bf16x8*)(&wlds[(size_t)((17 + (c)) * 64 + lane) << 3]); \
        bf16x8 w2_ = *(const bf16x8*)(&wlds[(size_t)((18 + (c)) * 64 + lane) << 3]); \
        bf16x8 w3_ = *(const bf16x8*)(&wlds[(size_t)((19 + (c)) * 64 + lane) << 3]); \
        a0 = __builtin_amdgcn_mfma_f32_16x16x32_bf16(hA, w0_, a0, 0, 0, 0); \
        a1 = __builtin_amdgcn_mfma_f32_16x16x32_bf16(hB, w1_, a1, 0, 0, 0); \
        a2 = __builtin_amdgcn_mfma_f32_16x16x32_bf16(hC, w2_, a2, 0, 0, 0); \
        a3 = __builtin_amdgcn_mfma_f32_16x16x32_bf16(hD, w3_, a3, 0, 0, 0); }
        HSTEP(0,  hb0,  hb1,  hb2,  hb3);
        HSTEP(4,  hb4,  hb5,  hb6,  hb7);
        HSTEP(8,  hb8,  hb9,  hb10, hb11);
        HSTEP(12, hb12, hb13, hb14, hb15);
        HSTEP(16, hb16, hb17, hb18, hb19);
        HSTEP(20, hb20, hb21, hb22, hb23);
        HSTEP(24, hb24, hb25, hb26, hb27);
        HSTEP(28, hb28, hb29, hb30, hb31);
#undef HSTEP
        f32x4 acc = (a0 + a1) + (a2 + a3);

        // per-wave transpose: C[batch q*4+r][gate-unit la] -> 4 gates per lane
#pragma unroll
        for (int r = 0; r < 4; r++) ex[w][q * 4 + r][la] = acc[r];
        float s0 = ex[w][m2][(v2 << 2) + 0];
        float s1 = ex[w][m2][(v2 << 2) + 1];
        float s2 = ex[w][m2][(v2 << 2) + 2];
        float s3 = ex[w][m2][(v2 << 2) + 3];

        float fg = sigm(s0 + bF);
        float ig = sigm(s1 + bI);
        float og = sigm(s2 + bO);
        float gg = tanhf(s3 + bG);
        c_reg = fg * c_reg + ig * gg;
        float hn = og * tanhf(c_reg);
        u16 hbv = f2bf(hn);
        hxh[b2][v2] = hbv;
        hxl[b2][v2] = f2bf(hn - bf2f(hbv));

        __syncthreads();   // h staging complete (wave0 reads all)

        // coalesced h writeout: wave 0, one 8B store per batch row.
        // hi: write-through agent atomics (MALL-visible before the flag);
        // lo: plain (only k_pred reads it, after a kernel boundary).
        if (tid < 64) {
            u64 hv = *(const u64*)&hxh[tid][0];
            u64 lv = *(const u64*)&hxl[tid][0];
            size_t ro = ((size_t)(t + 1) * B_ + tid) * H_ + (size_t)blk * 4;
            __hip_atomic_store((u64*)(hhi + ro), hv, __ATOMIC_RELAXED, __HIP_MEMORY_SCOPE_AGENT);
            *(u64*)(hlo + ro) = lv;
        }
        if (tid == 0) {
            // all step-t h stores were issued by THIS wave -> vmcnt covers them
            asm volatile("s_waitcnt vmcnt(0)" ::: "memory");
            __hip_atomic_fetch_add(&cnt[(blk & 7) * S_ + t], 1,
                                   __ATOMIC_RELAXED, __HIP_MEMORY_SCOPE_AGENT);
        }
        // hxh/hxl reuse safe: step-t+1 epilogue writes require passing
        // spin(t), which requires this block's flag(t), raised only after
        // hxh/hxl[t] were consumed by wave 0.
    }
}

// ---- final projection: out = H_all @ Wy^T + by (bf16 hi/lo, ~fp32 quality)
__global__ __launch_bounds__(256) void k_pred(
    const u16* __restrict__ ah, const u16* __restrict__ al,
    const u16* __restrict__ wyh, const u16* __restrict__ wyl,
    const float* __restrict__ by, float* __restrict__ out)
{
    const int tid = threadIdx.x;
    const int wv = tid >> 6;
    const int lane = tid & 63;
    const int la = lane & 15;
    const int kg = (lane >> 4) * 8;
    const int m0 = blockIdx.x * 64;
    const int n0 = blockIdx.y * 64 + wv * 16;

    const u16* bh = wyh + (size_t)(n0 + la) * H_ + kg;
    const u16* bl = wyl + (size_t)(n0 + la) * H_ + kg;

    f32x4 acc[4];
#pragma unroll
    for (int m = 0; m < 4; m++) acc[m] = (f32x4){0.f, 0.f, 0.f, 0.f};

    for (int k = 0; k < H_; k += 32) {
        bf16x8 bhh = *(const bf16x8*)(bh + k);
        bf16x8 bll = *(const bf16x8*)(bl + k);
#pragma unroll
        for (int m = 0; m < 4; m++) {
            size_t arow = (size_t)(m0 + m * 16 + la);
            bf16x8 aa  = *(const bf16x8*)(ah + arow * H_ + k + kg);
            bf16x8 aal = *(const bf16x8*)(al + arow * H_ + k + kg);
            acc[m] = __builtin_amdgcn_mfma_f32_16x16x32_bf16(aal, bhh, acc[m], 0, 0, 0);
            acc[m] = __builtin_amdgcn_mfma_f32_16x16x32_bf16(aa, bll, acc[m], 0, 0, 0);
            acc[m] = __builtin_amdgcn_mfma_f32_16x16x32_bf16(aa, bhh, acc[m], 0, 0, 0);
        }
    }

#pragma unroll
    for (int m = 0; m < 4; m++)
#pragma unroll
        for (int r = 0; r < 4; r++) {
            int row = m0 + m * 16 + (lane >> 4) * 4 + r;
            int col = n0 + la;
            out[(size_t)row * O_ + col] = acc[m][r] + by[col];
        }
}

// ---- host ------------------------------------------------------------------

extern "C" void kernel_launch(void* const* d_in, const int* in_sizes, int n_in,
                              void* d_out, int out_size, void* d_ws, size_t ws_size,
                              hipStream_t stream) {
    const float* x   = (const float*)d_in[0];
    const float* Wf  = (const float*)d_in[1];
    const float* bfv = (const float*)d_in[2];
    const float* Wi  = (const float*)d_in[3];
    const float* biv = (const float*)d_in[4];
    const float* Wo  = (const float*)d_in[5];
    const float* bov = (const float*)d_in[6];
    const float* Wg  = (const float*)d_in[7];
    const float* bgv = (const float*)d_in[8];
    const float* Wy  = (const float*)d_in[9];
    const float* by  = (const float*)d_in[10];
    float* out = (float*)d_out;

    char* ws = (char*)d_ws;
    size_t off = 0;
    auto alloc = [&](size_t bytes) {
        char* p = ws + off;
        off += (bytes + 255) & ~(size_t)255;
        return p;
    };
    u16*   Wall = (u16*)alloc((size_t)NG_ * C_ * 2);
    u16*   Wyhi = (u16*)alloc((size_t)O_ * H_ * 2);
    u16*   Wylo = (u16*)alloc((size_t)O_ * H_ * 2);
    u16*   xbf  = (u16*)alloc((size_t)S_ * B_ * I_ * 2);
    u16*   hhi  = (u16*)alloc((size_t)(S_ + 1) * B_ * H_ * 2);
    u16*   hlo  = (u16*)alloc((size_t)(S_ + 1) * B_ * H_ * 2);
    int*   cnt  = (int*)alloc((size_t)8 * S_ * 4);   // [8][S] spread counters

    (void)hipMemsetAsync(hhi, 0, (size_t)B_ * H_ * 2, stream);   // h(0) = 0
    (void)hipMemsetAsync(cnt, 0, (size_t)8 * S_ * 4, stream);    // step counters

    k_pack_w <<<3072, 256, 0, stream>>>(Wf, Wi, Wo, Wg, Wall);
    k_pack_wy<<<256,  256, 0, stream>>>(Wy, Wyhi, Wylo);
    k_pack_x <<<8192, 256, 0, stream>>>(x, xbf);

    k_lstm<<<256, 256, 0, stream>>>(Wall, xbf, bfv, biv, bov, bgv, hhi, hlo, cnt);

    k_pred<<<dim3(512, 8), 256, 0, stream>>>(hhi + (size_t)B_ * H_, hlo + (size_t)B_ * H_,
                                             Wyhi, Wylo, by, out);
}